// Round 8
// baseline (1260.447 us; speedup 1.0000x reference)
//
#include <hip/hip_runtime.h>

#define NN      524288      // nodes
#define NE      2097152     // edges
#define NGRAPH  16384
#define GSZ     32
#define PADR    45
#define F_IN    79
#define F_MID   138
#define F_OUT   128

#define NSTR    256         // cursor stripes for counting sort

typedef __attribute__((ext_vector_type(8))) short short8;
typedef __attribute__((ext_vector_type(4))) float f32x4;

__device__ __forceinline__ unsigned short f2b(float f) {
    union { float f; unsigned u; } v; v.f = f;
    unsigned r = v.u + 0x7FFF + ((v.u >> 16) & 1);   // RNE
    return (unsigned short)(r >> 16);
}
__device__ __forceinline__ float b2f(unsigned short u) {
    union { unsigned u; float f; } v; v.u = ((unsigned)u) << 16;
    return v.f;
}

// ---------------- degree count ----------------

__global__ void k_init_cnt(int* __restrict__ cnt) {
    int i = blockIdx.x * 256 + threadIdx.x;
    if (i < NN) cnt[i] = 1;                      // self loop
}

__global__ void k_count(const int* __restrict__ dst, int* __restrict__ cnt) {
    int e = blockIdx.x * 256 + threadIdx.x;
    if (e < NE) atomicAdd(&cnt[dst[e]], 1);
}

// ---------------- degree-balanced permutation (striped counting sort, DESCENDING = LPT) ----------------

__global__ void k_zero_hist(int* __restrict__ hist2) {
    int i = blockIdx.x * 256 + threadIdx.x;      // NSTR*64 entries
    hist2[i] = 0;
}

__global__ void k_hist2(const int* __restrict__ cnt, int* __restrict__ hist2) {
    int i = blockIdx.x * 256 + threadIdx.x;
    if (i < NN) {
        int d = min(cnt[i], 63);
        atomicAdd(&hist2[(blockIdx.x & (NSTR - 1)) * 64 + d], 1);
    }
}

__global__ void k_sscan(const int* __restrict__ hist2, int* __restrict__ cur) {
    __shared__ int s[256];
    int t = threadIdx.x;                         // thread t owns ranks [t*64, t*64+64)
    int sum = 0;
    for (int k = 0; k < 64; ++k) {
        int r = t * 64 + k;
        int d = 63 - (r >> 8), stripe = r & (NSTR - 1);
        sum += hist2[stripe * 64 + d];
    }
    s[t] = sum;
    __syncthreads();
    for (int off = 1; off < 256; off <<= 1) {
        int u = (t >= off) ? s[t - off] : 0;
        __syncthreads();
        s[t] += u;
        __syncthreads();
    }
    int run = s[t] - sum;
    for (int k = 0; k < 64; ++k) {
        int r = t * 64 + k;
        int d = 63 - (r >> 8), stripe = r & (NSTR - 1);
        cur[stripe * 64 + d] = run;
        run += hist2[stripe * 64 + d];
    }
}

__global__ void k_scatter2(const int* __restrict__ cnt, int* __restrict__ cur,
                           int* __restrict__ perm, int* __restrict__ ip,
                           float* __restrict__ dinvp) {
    int i = blockIdx.x * 256 + threadIdx.x;
    if (i < NN) {
        int d = min(cnt[i], 63);
        int pos = atomicAdd(&cur[(blockIdx.x & (NSTR - 1)) * 64 + d], 1);
        perm[pos] = i;
        ip[i] = pos;
        dinvp[pos] = rsqrtf((float)cnt[i]);
    }
}

// ---------------- CSR over permuted rows ----------------

__global__ void k_scan1p(const int* __restrict__ cnt, const int* __restrict__ perm,
                         int* __restrict__ rp, int* __restrict__ bsum) {
    __shared__ int s[256];
    int tid = threadIdx.x;
    size_t base = (size_t)blockIdx.x * 1024 + (size_t)tid * 4;
    int c0 = cnt[perm[base + 0]], c1 = cnt[perm[base + 1]];
    int c2 = cnt[perm[base + 2]], c3 = cnt[perm[base + 3]];
    int tsum = c0 + c1 + c2 + c3;
    s[tid] = tsum;
    __syncthreads();
    for (int off = 1; off < 256; off <<= 1) {
        int t = (tid >= off) ? s[tid - off] : 0;
        __syncthreads();
        s[tid] += t;
        __syncthreads();
    }
    int incl = s[tid];
    int ex = incl - tsum;
    rp[base + 0] = ex;
    rp[base + 1] = ex + c0;
    rp[base + 2] = ex + c0 + c1;
    rp[base + 3] = ex + c0 + c1 + c2;
    if (tid == 255) bsum[blockIdx.x] = incl;
}

__global__ void k_scan2(int* __restrict__ bsum) {
    __shared__ int s[512];
    int tid = threadIdx.x;
    int v = bsum[tid];
    s[tid] = v;
    __syncthreads();
    for (int off = 1; off < 512; off <<= 1) {
        int t = (tid >= off) ? s[tid - off] : 0;
        __syncthreads();
        s[tid] += t;
        __syncthreads();
    }
    bsum[tid] = s[tid] - v;                      // exclusive
}

__global__ void k_scan3(int* __restrict__ rp, const int* __restrict__ bsum,
                        int* __restrict__ cursor) {
    int i = blockIdx.x * 256 + threadIdx.x;
    if (i < NN) {
        int v = rp[i] + bsum[i >> 10];
        rp[i] = v;
        cursor[i] = v;
        if (i == 0) rp[NN] = NN + NE;
    }
}

__global__ void k_fill_self(int* __restrict__ cursor, int* __restrict__ col) {
    int t = blockIdx.x * 256 + threadIdx.x;
    if (t < NN) { int s = atomicAdd(&cursor[t], 1); col[s] = t; }
}

__global__ void k_fill_edges(const int* __restrict__ src, const int* __restrict__ dst,
                             const int* __restrict__ ip,
                             int* __restrict__ cursor, int* __restrict__ col) {
    int e = blockIdx.x * 256 + threadIdx.x;
    if (e < NE) {
        int r = ip[dst[e]], c = ip[src[e]];
        int s = atomicAdd(&cursor[r], 1);
        col[s] = c;
    }
}

// ---------------- weight / bias / input prep ----------------

__global__ void k_wconv(const float* __restrict__ W, unsigned short* __restrict__ WT,
                        int Fin, int Fout, int LDK) {
    int c = blockIdx.x;
    int k = threadIdx.x;
    float v = (k < Fin && c < Fout) ? W[(size_t)k * Fout + c] : 0.f;
    WT[(size_t)c * LDK + k] = f2b(v);
}

__global__ void k_bpad3(const float* __restrict__ b1, const float* __restrict__ b2,
                        const float* __restrict__ b3, float* __restrict__ bp) {
    int i = threadIdx.x;
    const float* b = (blockIdx.x == 0) ? b1 : (blockIdx.x == 1) ? b2 : b3;
    bp[blockIdx.x * 144 + i] = (i < F_MID) ? b[i] : 0.f;
}

// Xt[ip[n]][c] = bf16(dinv[n] * x[n][c]), stride 80
__global__ void k_xconv(const float* __restrict__ x, const int* __restrict__ ip,
                        const float* __restrict__ dinvp, unsigned short* __restrict__ Xt) {
    int n = blockIdx.x * 4 + threadIdx.y;
    int c = threadIdx.x;            // 0..79
    int t = ip[n];
    float d = dinvp[t];
    float v = (c < F_IN) ? d * x[(size_t)n * F_IN + c] : 0.f;
    Xt[(size_t)t * 80 + c] = f2b(v);
}

// ---------------- fused layer: gather-aggregate + MFMA GEMM (permuted space) ----------------
// 256 threads (4 waves), 64 rows/block. Gather unrolled x4 with fully staged loads
// (20 outstanding 16B loads/wave) to attack memory latency with ILP.
template<int SIN, int NT, int MODE>
__global__ __launch_bounds__(256, 2) void
k_fused(const unsigned short* __restrict__ Hin, const unsigned short* __restrict__ WT,
        const float* __restrict__ bias, void* __restrict__ Yout,
        const int* __restrict__ rp, const int* __restrict__ col,
        const float* __restrict__ dinvp, const int* __restrict__ perm) {
    constexpr int KSFULL = SIN / 32;             // 80->2, 144->4
    constexpr int KSTEPS = KSFULL + 1;           // incl. partial step
    constexpr int WROWS = NT * 16;
    constexpr int ROWB = SIN * 2;                // row bytes (160 / 288)
    constexpr int SWZLIM = ROWB & ~127;          // swizzle only full-128B region
    __shared__ __align__(16) unsigned short Ws[WROWS * SIN];

    const int tid = threadIdx.x;
    constexpr int CH = WROWS * SIN / 8;          // 16B chunks
    for (int i = tid; i < CH; i += 256) {
        int r = i / (SIN / 8), cc = i % (SIN / 8);
        int bo = cc * 16;
        int so = (bo < SWZLIM) ? (bo ^ ((r & 7) << 4)) : bo;
        *(f32x4*)((char*)Ws + (size_t)r * ROWB + so) =
            *(const f32x4*)&WT[(size_t)r * SIN + cc * 8];
    }

    const int wv = tid >> 6, lane = tid & 63;
    const int lrow = lane & 15, kg = lane >> 4;
    const int row = blockIdx.x * 64 + wv * 16 + lrow;

    const int beg = rp[row], end = rp[row + 1];

    float acc[KSTEPS][8];
#pragma unroll
    for (int ks = 0; ks < KSTEPS; ++ks)
#pragma unroll
        for (int e = 0; e < 8; ++e) acc[ks][e] = 0.f;

    // ---- gather loop, unrolled x4, loads fully staged before accumulation ----
    int s = beg;
    for (; s + 3 < end; s += 4) {
        int j0 = col[s], j1 = col[s + 1], j2 = col[s + 2], j3 = col[s + 3];
        const unsigned short* h0 = Hin + (size_t)j0 * SIN + kg * 8;
        const unsigned short* h1 = Hin + (size_t)j1 * SIN + kg * 8;
        const unsigned short* h2 = Hin + (size_t)j2 * SIN + kg * 8;
        const unsigned short* h3 = Hin + (size_t)j3 * SIN + kg * 8;
        short8 v0[KSTEPS], v1[KSTEPS], v2[KSTEPS], v3[KSTEPS];
#pragma unroll
        for (int ks = 0; ks < KSFULL; ++ks) {
            v0[ks] = *(const short8*)(h0 + ks * 32);
            v1[ks] = *(const short8*)(h1 + ks * 32);
            v2[ks] = *(const short8*)(h2 + ks * 32);
            v3[ks] = *(const short8*)(h3 + ks * 32);
        }
        if (kg < 2) {
            v0[KSFULL] = *(const short8*)(h0 + KSFULL * 32);
            v1[KSFULL] = *(const short8*)(h1 + KSFULL * 32);
            v2[KSFULL] = *(const short8*)(h2 + KSFULL * 32);
            v3[KSFULL] = *(const short8*)(h3 + KSFULL * 32);
        }
#pragma unroll
        for (int ks = 0; ks < KSFULL; ++ks)
#pragma unroll
            for (int e = 0; e < 8; ++e)
                acc[ks][e] += (b2f((unsigned short)v0[ks][e]) + b2f((unsigned short)v1[ks][e]))
                            + (b2f((unsigned short)v2[ks][e]) + b2f((unsigned short)v3[ks][e]));
        if (kg < 2) {
#pragma unroll
            for (int e = 0; e < 8; ++e)
                acc[KSFULL][e] += (b2f((unsigned short)v0[KSFULL][e]) + b2f((unsigned short)v1[KSFULL][e]))
                                + (b2f((unsigned short)v2[KSFULL][e]) + b2f((unsigned short)v3[KSFULL][e]));
        }
    }
    for (; s < end; ++s) {
        int j = col[s];
        const unsigned short* hj = Hin + (size_t)j * SIN + kg * 8;
#pragma unroll
        for (int ks = 0; ks < KSFULL; ++ks) {
            short8 v = *(const short8*)(hj + ks * 32);
#pragma unroll
            for (int e = 0; e < 8; ++e) acc[ks][e] += b2f((unsigned short)v[e]);
        }
        if (kg < 2) {
            short8 v = *(const short8*)(hj + KSFULL * 32);
#pragma unroll
            for (int e = 0; e < 8; ++e) acc[KSFULL][e] += b2f((unsigned short)v[e]);
        }
    }

    const float di = dinvp[row];
    short8 a[KSTEPS];
#pragma unroll
    for (int ks = 0; ks < KSTEPS; ++ks)
#pragma unroll
        for (int e = 0; e < 8; ++e)
            a[ks][e] = (short)f2b(di * acc[ks][e]);
    if (kg >= 2) {
#pragma unroll
        for (int e = 0; e < 8; ++e) a[KSTEPS - 1][e] = 0;
    }

    __syncthreads();                             // Ws ready

    f32x4 acc2[NT];
#pragma unroll
    for (int n = 0; n < NT; ++n) acc2[n] = (f32x4){0.f, 0.f, 0.f, 0.f};

#pragma unroll
    for (int ks = 0; ks < KSTEPS; ++ks) {
        const int bo = ks * 64 + kg * 16;
#pragma unroll
        for (int n = 0; n < NT; ++n) {
            int r = n * 16 + lrow;
            short8 b;
            if (ks == KSTEPS - 1 && kg >= 2) {
                b = a[KSTEPS - 1];
            } else {
                int so = (bo < SWZLIM) ? (bo ^ ((r & 7) << 4)) : bo;
                b = *(const short8*)((const char*)Ws + (size_t)r * ROWB + so);
            }
            acc2[n] = __builtin_amdgcn_mfma_f32_16x16x32_bf16(a[ks], b, acc2[n], 0, 0, 0);
        }
    }

    // ---- epilogue (non-temporal stores) ----
    const int t0 = blockIdx.x * 64 + wv * 16 + kg * 4;
    if (MODE == 0) {
        unsigned short* Yp = (unsigned short*)Yout;
        float d4[4];
#pragma unroll
        for (int j = 0; j < 4; ++j) d4[j] = dinvp[t0 + j];
#pragma unroll
        for (int n = 0; n < NT; ++n) {
            int c = n * 16 + lrow;
            float bv = bias[c];
#pragma unroll
            for (int j = 0; j < 4; ++j)
                __builtin_nontemporal_store(f2b(d4[j] * (acc2[n][j] + bv)),
                                            &Yp[(size_t)(t0 + j) * 144 + c]);
        }
    } else {
        float* Yo = (float*)Yout;
        int pr[4];
#pragma unroll
        for (int j = 0; j < 4; ++j) pr[j] = perm[t0 + j];
#pragma unroll
        for (int n = 0; n < NT; ++n) {
            int c = n * 16 + lrow;
            float bv = bias[c];
#pragma unroll
            for (int j = 0; j < 4; ++j) {
                size_t o = ((size_t)(pr[j] >> 5) * PADR + (pr[j] & 31)) * F_OUT + c;
                __builtin_nontemporal_store(acc2[n][j] + bv, &Yo[o]);
            }
        }
    }
}

__global__ void k_padzero(float* __restrict__ out) {
    size_t idx = (size_t)blockIdx.x * 256 + threadIdx.x;
    const size_t total = (size_t)NGRAPH * (PADR - GSZ) * F_OUT;
    if (idx < total) {
        size_t b  = idx / ((PADR - GSZ) * F_OUT);
        int rem   = (int)(idx % ((PADR - GSZ) * F_OUT));
        int r     = GSZ + rem / F_OUT;
        int d     = rem % F_OUT;
        __builtin_nontemporal_store(0.f, &out[((size_t)b * PADR + r) * (size_t)F_OUT + d]);
    }
}

// ---------------- launch ----------------

static inline size_t align256(size_t x) { return (x + 255) & ~(size_t)255; }

extern "C" void kernel_launch(void* const* d_in, const int* in_sizes, int n_in,
                              void* d_out, int out_size, void* d_ws, size_t ws_size,
                              hipStream_t stream) {
    const float* x   = (const float*)d_in[0];
    const int* ei    = (const int*)d_in[1];
    const int* src   = ei;            // edge_index[0]
    const int* dst   = ei + NE;       // edge_index[1]
    const float* W1  = (const float*)d_in[2];
    const float* b1  = (const float*)d_in[3];
    const float* W2  = (const float*)d_in[4];
    const float* b2  = (const float*)d_in[5];
    const float* W3  = (const float*)d_in[6];
    const float* b3  = (const float*)d_in[7];
    const float* W4  = (const float*)d_in[8];
    const float* b4  = (const float*)d_in[9];

    // workspace layout
    char* p = (char*)d_ws;
    unsigned short* HA = (unsigned short*)p;  p += align256((size_t)NN * 144 * 2);
    unsigned short* HB = (unsigned short*)p;  p += align256((size_t)NN * 144 * 2);
    int* cnt    = (int*)p;              p += align256((size_t)NN * sizeof(int));
    int* rp     = (int*)p;              p += align256(((size_t)NN + 1) * sizeof(int));
    int* cursor = (int*)p;              p += align256((size_t)NN * sizeof(int));
    int* colix  = (int*)p;              p += align256((size_t)(NN + NE) * sizeof(int));
    float* dinvp= (float*)p;            p += align256((size_t)NN * sizeof(float));
    int* perm   = (int*)p;              p += align256((size_t)NN * sizeof(int));
    int* ip     = (int*)p;              p += align256((size_t)NN * sizeof(int));
    int* hist2  = (int*)p;              p += align256((size_t)NSTR * 64 * sizeof(int));
    int* cur    = (int*)p;              p += align256((size_t)NSTR * 64 * sizeof(int));
    int* bsum   = (int*)p;              p += align256(512 * sizeof(int));
    unsigned short* WT1 = (unsigned short*)p; p += align256(144 * 80 * 2);
    unsigned short* WT2 = (unsigned short*)p; p += align256(144 * 144 * 2);
    unsigned short* WT3 = (unsigned short*)p; p += align256(144 * 144 * 2);
    unsigned short* WT4 = (unsigned short*)p; p += align256(128 * 144 * 2);
    float* bp   = (float*)p;            p += align256(3 * 144 * sizeof(float));
    (void)ws_size; (void)n_in; (void)in_sizes; (void)out_size;

    unsigned short* Xt = (unsigned short*)d_out;   // layer-1 bf16 table in d_out scratch

    // ---- degree count + striped counting sort (descending = LPT) ----
    k_init_cnt<<<NN / 256, 256, 0, stream>>>(cnt);
    k_count<<<NE / 256, 256, 0, stream>>>(dst, cnt);
    k_zero_hist<<<NSTR * 64 / 256, 256, 0, stream>>>(hist2);
    k_hist2<<<NN / 256, 256, 0, stream>>>(cnt, hist2);
    k_sscan<<<1, 256, 0, stream>>>(hist2, cur);
    k_scatter2<<<NN / 256, 256, 0, stream>>>(cnt, cur, perm, ip, dinvp);

    // ---- CSR in permuted space ----
    k_scan1p<<<NN / 1024, 256, 0, stream>>>(cnt, perm, rp, bsum);
    k_scan2<<<1, 512, 0, stream>>>(bsum);
    k_scan3<<<NN / 256, 256, 0, stream>>>(rp, bsum, cursor);
    k_fill_self<<<NN / 256, 256, 0, stream>>>(cursor, colix);
    k_fill_edges<<<NE / 256, 256, 0, stream>>>(src, dst, ip, cursor, colix);

    // ---- weights / bias / input prep ----
    k_wconv<<<144, 80, 0, stream>>>(W1, WT1, F_IN, F_MID, 80);
    k_wconv<<<144, 144, 0, stream>>>(W2, WT2, F_MID, F_MID, 144);
    k_wconv<<<144, 144, 0, stream>>>(W3, WT3, F_MID, F_MID, 144);
    k_wconv<<<128, 144, 0, stream>>>(W4, WT4, F_MID, F_OUT, 144);
    k_bpad3<<<3, 144, 0, stream>>>(b1, b2, b3, bp);
    {
        dim3 b(80, 4);
        k_xconv<<<NN / 4, b, 0, stream>>>(x, ip, dinvp, Xt);
    }

    const int blocks = NN / 64;   // 8192 (64 rows per 256-thread block)

    // layer 1: Xt[80] -> HB[144]
    k_fused<80, 9, 0><<<blocks, 256, 0, stream>>>(Xt, WT1, bp, HB, rp, colix, dinvp, perm);
    // layer 2: HB -> HA
    k_fused<144, 9, 0><<<blocks, 256, 0, stream>>>(HB, WT2, bp + 144, HA, rp, colix, dinvp, perm);
    // layer 3: HA -> HB
    k_fused<144, 9, 0><<<blocks, 256, 0, stream>>>(HA, WT3, bp + 288, HB, rp, colix, dinvp, perm);
    // layer 4: HB -> padded fp32 d_out (scatter via perm)
    k_fused<144, 8, 1><<<blocks, 256, 0, stream>>>(HB, WT4, b4, d_out, rp, colix, dinvp, perm);
    // zero pad rows
    {
        size_t total = (size_t)NGRAPH * (PADR - GSZ) * F_OUT;
        k_padzero<<<(unsigned)((total + 255) / 256), 256, 0, stream>>>((float*)d_out);
    }
}

// Round 9
// 1091.613 us; speedup vs baseline: 1.1547x; 1.1547x over previous
//
#include <hip/hip_runtime.h>

#define NN      524288      // nodes
#define NE      2097152     // edges
#define NGRAPH  16384
#define GSZ     32
#define PADR    45
#define F_IN    79
#define F_MID   138
#define F_OUT   128

#define NSTR    256         // cursor stripes for counting sort
#define SIN     80          // table stride (79 X cols + 1 "ones" col)

typedef __attribute__((ext_vector_type(8))) short short8;
typedef __attribute__((ext_vector_type(4))) float f32x4;

__device__ __forceinline__ unsigned short f2b(float f) {
    union { float f; unsigned u; } v; v.f = f;
    unsigned r = v.u + 0x7FFF + ((v.u >> 16) & 1);   // RNE
    return (unsigned short)(r >> 16);
}
__device__ __forceinline__ float b2f(unsigned short u) {
    union { unsigned u; float f; } v; v.u = ((unsigned)u) << 16;
    return v.f;
}

// ---------------- degree count ----------------

__global__ void k_init_cnt(int* __restrict__ cnt) {
    int i = blockIdx.x * 256 + threadIdx.x;
    if (i < NN) cnt[i] = 1;                      // self loop
}

__global__ void k_count(const int* __restrict__ dst, int* __restrict__ cnt) {
    int e = blockIdx.x * 256 + threadIdx.x;
    if (e < NE) atomicAdd(&cnt[dst[e]], 1);
}

// ---------------- degree-balanced permutation (striped counting sort, DESCENDING = LPT) ----------------

__global__ void k_zero_hist(int* __restrict__ hist2) {
    int i = blockIdx.x * 256 + threadIdx.x;      // NSTR*64 entries
    hist2[i] = 0;
}

__global__ void k_hist2(const int* __restrict__ cnt, int* __restrict__ hist2) {
    int i = blockIdx.x * 256 + threadIdx.x;
    if (i < NN) {
        int d = min(cnt[i], 63);
        atomicAdd(&hist2[(blockIdx.x & (NSTR - 1)) * 64 + d], 1);
    }
}

__global__ void k_sscan(const int* __restrict__ hist2, int* __restrict__ cur) {
    __shared__ int s[256];
    int t = threadIdx.x;                         // thread t owns ranks [t*64, t*64+64)
    int sum = 0;
    for (int k = 0; k < 64; ++k) {
        int r = t * 64 + k;
        int d = 63 - (r >> 8), stripe = r & (NSTR - 1);
        sum += hist2[stripe * 64 + d];
    }
    s[t] = sum;
    __syncthreads();
    for (int off = 1; off < 256; off <<= 1) {
        int u = (t >= off) ? s[t - off] : 0;
        __syncthreads();
        s[t] += u;
        __syncthreads();
    }
    int run = s[t] - sum;
    for (int k = 0; k < 64; ++k) {
        int r = t * 64 + k;
        int d = 63 - (r >> 8), stripe = r & (NSTR - 1);
        cur[stripe * 64 + d] = run;
        run += hist2[stripe * 64 + d];
    }
}

__global__ void k_scatter2(const int* __restrict__ cnt, int* __restrict__ cur,
                           int* __restrict__ perm, int* __restrict__ ip,
                           float* __restrict__ dinvp) {
    int i = blockIdx.x * 256 + threadIdx.x;
    if (i < NN) {
        int d = min(cnt[i], 63);
        int pos = atomicAdd(&cur[(NSTR - 1 & blockIdx.x) * 64 + d], 1);
        perm[pos] = i;
        ip[i] = pos;
        dinvp[pos] = rsqrtf((float)cnt[i]);
    }
}

// ---------------- CSR over permuted rows (EDGES ONLY, no self loops) ----------------

__global__ void k_scan1p(const int* __restrict__ cnt, const int* __restrict__ perm,
                         int* __restrict__ rp, int* __restrict__ bsum) {
    __shared__ int s[256];
    int tid = threadIdx.x;
    size_t base = (size_t)blockIdx.x * 1024 + (size_t)tid * 4;
    int c0 = cnt[perm[base + 0]] - 1, c1 = cnt[perm[base + 1]] - 1;
    int c2 = cnt[perm[base + 2]] - 1, c3 = cnt[perm[base + 3]] - 1;
    int tsum = c0 + c1 + c2 + c3;
    s[tid] = tsum;
    __syncthreads();
    for (int off = 1; off < 256; off <<= 1) {
        int t = (tid >= off) ? s[tid - off] : 0;
        __syncthreads();
        s[tid] += t;
        __syncthreads();
    }
    int incl = s[tid];
    int ex = incl - tsum;
    rp[base + 0] = ex;
    rp[base + 1] = ex + c0;
    rp[base + 2] = ex + c0 + c1;
    rp[base + 3] = ex + c0 + c1 + c2;
    if (tid == 255) bsum[blockIdx.x] = incl;
}

__global__ void k_scan2(int* __restrict__ bsum) {
    __shared__ int s[512];
    int tid = threadIdx.x;
    int v = bsum[tid];
    s[tid] = v;
    __syncthreads();
    for (int off = 1; off < 512; off <<= 1) {
        int t = (tid >= off) ? s[tid - off] : 0;
        __syncthreads();
        s[tid] += t;
        __syncthreads();
    }
    bsum[tid] = s[tid] - v;                      // exclusive
}

__global__ void k_scan3(int* __restrict__ rp, const int* __restrict__ bsum,
                        int* __restrict__ cursor) {
    int i = blockIdx.x * 256 + threadIdx.x;
    if (i < NN) {
        int v = rp[i] + bsum[i >> 10];
        rp[i] = v;
        cursor[i] = v;
        if (i == 0) rp[NN] = NE;
    }
}

__global__ void k_fill_edges(const int* __restrict__ src, const int* __restrict__ dst,
                             const int* __restrict__ ip,
                             int* __restrict__ cursor, int* __restrict__ col) {
    int e = blockIdx.x * 256 + threadIdx.x;
    if (e < NE) {
        int r = ip[dst[e]], c = ip[src[e]];
        int s = atomicAdd(&cursor[r], 1);
        col[s] = c;
    }
}

// ---------------- small fp32 matmul: C[M,N] = A[M,K] * B[K,N]; grid=M, block=N ----------------

__global__ void genmm(const float* __restrict__ A, const float* __restrict__ B,
                      float* __restrict__ C, int K, int N) {
    int m = blockIdx.x, n = threadIdx.x;
    float s = 0.f;
    for (int k = 0; k < K; ++k) s += A[(size_t)m * K + k] * B[(size_t)k * N + n];
    C[(size_t)m * N + n] = s;
}

// ---------------- build Wx^T [128 out][96 k] bf16 ----------------
// k<79: Wc[k][c]; 79:0 (u4 slot); 80:r3 (pairs u1); 81:r2 (u2); 82:r1 (u3); 83:b4; >=84:0
__global__ void k_wx(const float* __restrict__ Wc, const float* __restrict__ r1,
                     const float* __restrict__ r2, const float* __restrict__ r3,
                     const float* __restrict__ b4, unsigned short* __restrict__ WxT) {
    int c = blockIdx.x, k = threadIdx.x;
    float v = 0.f;
    if (k < 79)       v = Wc[(size_t)k * 128 + c];
    else if (k == 80) v = r3[c];
    else if (k == 81) v = r2[c];
    else if (k == 82) v = r1[c];
    else if (k == 83) v = b4[c];
    WxT[(size_t)c * 96 + k] = f2b(v);
}

// Xt[ip[n]][c] = bf16(dinv * x[n][c]); col 79 = bf16(dinv * 1)
__global__ void k_xconv(const float* __restrict__ x, const int* __restrict__ ip,
                        const float* __restrict__ dinvp, unsigned short* __restrict__ Xt) {
    int n = blockIdx.x * 4 + threadIdx.y;
    int c = threadIdx.x;            // 0..79
    int t = ip[n];
    float d = dinvp[t];
    float v = (c < F_IN) ? d * x[(size_t)n * F_IN + c] : d;
    Xt[(size_t)t * SIN + c] = f2b(v);
}

// ---------------- pure aggregation: T_{k+1} = A T_k on 80-col bf16 table ----------------
// Hin rows are prescaled by dinv. out val = dinv*sum; store = PRESCALE? dinv*val : val.
// usnap (if non-null) captures col-79 T-value (= A^k 1).
template<int PRESCALE>
__global__ __launch_bounds__(512) void
k_agg_s(const unsigned short* __restrict__ Hin, unsigned short* __restrict__ Hout,
        float* __restrict__ usnap,
        const int* __restrict__ rp, const int* __restrict__ col,
        const float* __restrict__ dinvp) {
    const int tid = threadIdx.x;
    const int wv = tid >> 6, lane = tid & 63;
    const int lrow = lane & 15, kg = lane >> 4;
    const int row = blockIdx.x * 128 + wv * 16 + lrow;
    const int beg = rp[row], end = rp[row + 1];

    float acc[3][8];
#pragma unroll
    for (int ks = 0; ks < 3; ++ks)
#pragma unroll
        for (int e = 0; e < 8; ++e) acc[ks][e] = 0.f;

    // self row: coalesced read of own row
    {
        const unsigned short* hj = Hin + (size_t)row * SIN + kg * 8;
        short8 v0 = *(const short8*)(hj);
        short8 v1 = *(const short8*)(hj + 32);
#pragma unroll
        for (int e = 0; e < 8; ++e) acc[0][e] += b2f((unsigned short)v0[e]);
#pragma unroll
        for (int e = 0; e < 8; ++e) acc[1][e] += b2f((unsigned short)v1[e]);
        if (kg < 2) {
            short8 v2 = *(const short8*)(hj + 64);
#pragma unroll
            for (int e = 0; e < 8; ++e) acc[2][e] += b2f((unsigned short)v2[e]);
        }
    }

    // edge gather, 2-edge staged
    int s = beg;
    for (; s + 1 < end; s += 2) {
        int j0 = col[s], j1 = col[s + 1];
        const unsigned short* h0 = Hin + (size_t)j0 * SIN + kg * 8;
        const unsigned short* h1 = Hin + (size_t)j1 * SIN + kg * 8;
        short8 a0 = *(const short8*)(h0);
        short8 b0 = *(const short8*)(h0 + 32);
        short8 a1 = *(const short8*)(h1);
        short8 b1 = *(const short8*)(h1 + 32);
        if (kg < 2) {
            short8 c0 = *(const short8*)(h0 + 64);
            short8 c1 = *(const short8*)(h1 + 64);
#pragma unroll
            for (int e = 0; e < 8; ++e)
                acc[2][e] += b2f((unsigned short)c0[e]) + b2f((unsigned short)c1[e]);
        }
#pragma unroll
        for (int e = 0; e < 8; ++e)
            acc[0][e] += b2f((unsigned short)a0[e]) + b2f((unsigned short)a1[e]);
#pragma unroll
        for (int e = 0; e < 8; ++e)
            acc[1][e] += b2f((unsigned short)b0[e]) + b2f((unsigned short)b1[e]);
    }
    if (s < end) {
        int j = col[s];
        const unsigned short* hj = Hin + (size_t)j * SIN + kg * 8;
        short8 v0 = *(const short8*)(hj);
        short8 v1 = *(const short8*)(hj + 32);
#pragma unroll
        for (int e = 0; e < 8; ++e) acc[0][e] += b2f((unsigned short)v0[e]);
#pragma unroll
        for (int e = 0; e < 8; ++e) acc[1][e] += b2f((unsigned short)v1[e]);
        if (kg < 2) {
            short8 v2 = *(const short8*)(hj + 64);
#pragma unroll
            for (int e = 0; e < 8; ++e) acc[2][e] += b2f((unsigned short)v2[e]);
        }
    }

    const float di = dinvp[row];
    unsigned short* ho = Hout + (size_t)row * SIN + kg * 8;
#pragma unroll
    for (int ks = 0; ks < 2; ++ks) {
        short8 o;
#pragma unroll
        for (int e = 0; e < 8; ++e) {
            float val = di * acc[ks][e];
            o[e] = (short)f2b(PRESCALE ? di * val : val);
        }
        *(short8*)(ho + ks * 32) = o;
    }
    if (kg < 2) {
        short8 o;
#pragma unroll
        for (int e = 0; e < 8; ++e) {
            float val = di * acc[2][e];
            o[e] = (short)f2b(PRESCALE ? di * val : val);
        }
        *(short8*)(ho + 64) = o;
        if (usnap != nullptr && kg == 1)
            usnap[row] = di * acc[2][7];         // col 79 T-value = A^k 1
    }
}

// ---------------- final GEMM: Y = [T4 | u1 u2 u3 1] @ Wx, padded fp32 output ----------------
__global__ __launch_bounds__(512) void
k_out(const unsigned short* __restrict__ T4, const unsigned short* __restrict__ WxT,
      const float* __restrict__ u1, const float* __restrict__ u2,
      const float* __restrict__ u3, float* __restrict__ Yo,
      const int* __restrict__ perm) {
    constexpr int ROWB = 192;                    // 96 cols * 2B
    __shared__ __align__(16) unsigned short Ws[128 * 96];

    const int tid = threadIdx.x;
    for (int i = tid; i < 128 * 96 / 8; i += 512) {
        int r = i / 12, cc = i % 12;
        int bo = cc * 16;
        int so = (bo < 128) ? (bo ^ ((r & 7) << 4)) : bo;
        *(f32x4*)((char*)Ws + (size_t)r * ROWB + so) =
            *(const f32x4*)&WxT[(size_t)r * 96 + cc * 8];
    }

    const int wv = tid >> 6, lane = tid & 63;
    const int lrow = lane & 15, kg = lane >> 4;
    const int row = blockIdx.x * 128 + wv * 16 + lrow;

    short8 a[3];
    const unsigned short* hr = T4 + (size_t)row * SIN + kg * 8;
    a[0] = *(const short8*)(hr);
    a[1] = *(const short8*)(hr + 32);
    if (kg < 2) {
        a[2] = *(const short8*)(hr + 64);
    } else if (kg == 2) {
        a[2][0] = (short)f2b(u1[row]);
        a[2][1] = (short)f2b(u2[row]);
        a[2][2] = (short)f2b(u3[row]);
        a[2][3] = (short)0x3F80;                 // bf16(1.0)
#pragma unroll
        for (int e = 4; e < 8; ++e) a[2][e] = 0;
    } else {
#pragma unroll
        for (int e = 0; e < 8; ++e) a[2][e] = 0;
    }

    __syncthreads();

    f32x4 acc2[8];
#pragma unroll
    for (int n = 0; n < 8; ++n) acc2[n] = (f32x4){0.f, 0.f, 0.f, 0.f};

#pragma unroll
    for (int ks = 0; ks < 3; ++ks) {
        const int bo = ks * 64 + kg * 16;
#pragma unroll
        for (int n = 0; n < 8; ++n) {
            int r = n * 16 + lrow;
            int so = (bo < 128) ? (bo ^ ((r & 7) << 4)) : bo;
            short8 b = *(const short8*)((const char*)Ws + (size_t)r * ROWB + so);
            acc2[n] = __builtin_amdgcn_mfma_f32_16x16x32_bf16(a[ks], b, acc2[n], 0, 0, 0);
        }
    }

    const int t0 = blockIdx.x * 128 + wv * 16 + kg * 4;
    int pr[4];
#pragma unroll
    for (int j = 0; j < 4; ++j) pr[j] = perm[t0 + j];
#pragma unroll
    for (int n = 0; n < 8; ++n) {
        int c = n * 16 + lrow;
#pragma unroll
        for (int j = 0; j < 4; ++j) {
            size_t o = ((size_t)(pr[j] >> 5) * PADR + (pr[j] & 31)) * F_OUT + c;
            __builtin_nontemporal_store(acc2[n][j], &Yo[o]);
        }
    }
}

__global__ void k_padzero(float* __restrict__ out) {
    size_t idx = (size_t)blockIdx.x * 256 + threadIdx.x;
    const size_t total = (size_t)NGRAPH * (PADR - GSZ) * F_OUT;
    if (idx < total) {
        size_t b  = idx / ((PADR - GSZ) * F_OUT);
        int rem   = (int)(idx % ((PADR - GSZ) * F_OUT));
        int r     = GSZ + rem / F_OUT;
        int d     = rem % F_OUT;
        __builtin_nontemporal_store(0.f, &out[((size_t)b * PADR + r) * (size_t)F_OUT + d]);
    }
}

// ---------------- launch ----------------

static inline size_t align256(size_t x) { return (x + 255) & ~(size_t)255; }

extern "C" void kernel_launch(void* const* d_in, const int* in_sizes, int n_in,
                              void* d_out, int out_size, void* d_ws, size_t ws_size,
                              hipStream_t stream) {
    const float* x   = (const float*)d_in[0];
    const int* ei    = (const int*)d_in[1];
    const int* src   = ei;            // edge_index[0]
    const int* dst   = ei + NE;       // edge_index[1]
    const float* W1  = (const float*)d_in[2];
    const float* b1  = (const float*)d_in[3];
    const float* W2  = (const float*)d_in[4];
    const float* b2  = (const float*)d_in[5];
    const float* W3  = (const float*)d_in[6];
    const float* b3  = (const float*)d_in[7];
    const float* W4  = (const float*)d_in[8];
    const float* b4  = (const float*)d_in[9];

    // workspace layout
    char* p = (char*)d_ws;
    unsigned short* HA = (unsigned short*)p;  p += align256((size_t)NN * SIN * 2);
    unsigned short* HB = (unsigned short*)p;  p += align256((size_t)NN * SIN * 2);
    int* cnt    = (int*)p;              p += align256((size_t)NN * sizeof(int));
    int* rp     = (int*)p;              p += align256(((size_t)NN + 1) * sizeof(int));
    int* cursor = (int*)p;              p += align256((size_t)NN * sizeof(int));
    int* colix  = (int*)p;              p += align256((size_t)NE * sizeof(int));
    float* dinvp= (float*)p;            p += align256((size_t)NN * sizeof(float));
    int* perm   = (int*)p;              p += align256((size_t)NN * sizeof(int));
    int* ip     = (int*)p;              p += align256((size_t)NN * sizeof(int));
    int* hist2  = (int*)p;              p += align256((size_t)NSTR * 64 * sizeof(int));
    int* cur    = (int*)p;              p += align256((size_t)NSTR * 64 * sizeof(int));
    int* bsum   = (int*)p;              p += align256(512 * sizeof(int));
    float* u1   = (float*)p;            p += align256((size_t)NN * sizeof(float));
    float* u2   = (float*)p;            p += align256((size_t)NN * sizeof(float));
    float* u3   = (float*)p;            p += align256((size_t)NN * sizeof(float));
    float* W34  = (float*)p;            p += align256(138 * 128 * sizeof(float));
    float* U2   = (float*)p;            p += align256(138 * 128 * sizeof(float));
    float* Wc   = (float*)p;            p += align256(79 * 128 * sizeof(float));
    float* t1   = (float*)p;            p += align256(138 * sizeof(float));
    float* r1   = (float*)p;            p += align256(128 * sizeof(float));
    float* r2   = (float*)p;            p += align256(128 * sizeof(float));
    float* r3   = (float*)p;            p += align256(128 * sizeof(float));
    unsigned short* WxT = (unsigned short*)p; p += align256(128 * 96 * 2);
    (void)ws_size; (void)n_in; (void)in_sizes; (void)out_size;

    unsigned short* Xt = (unsigned short*)d_out;   // T0 table in d_out scratch

    // ---- degree count + striped counting sort (descending = LPT) ----
    k_init_cnt<<<NN / 256, 256, 0, stream>>>(cnt);
    k_count<<<NE / 256, 256, 0, stream>>>(dst, cnt);
    k_zero_hist<<<NSTR * 64 / 256, 256, 0, stream>>>(hist2);
    k_hist2<<<NN / 256, 256, 0, stream>>>(cnt, hist2);
    k_sscan<<<1, 256, 0, stream>>>(hist2, cur);
    k_scatter2<<<NN / 256, 256, 0, stream>>>(cnt, cur, perm, ip, dinvp);

    // ---- CSR in permuted space (edges only) ----
    k_scan1p<<<NN / 1024, 256, 0, stream>>>(cnt, perm, rp, bsum);
    k_scan2<<<1, 512, 0, stream>>>(bsum);
    k_scan3<<<NN / 256, 256, 0, stream>>>(rp, bsum, cursor);
    k_fill_edges<<<NE / 256, 256, 0, stream>>>(src, dst, ip, cursor, colix);

    // ---- composite weights (tiny fp32 matmuls) ----
    genmm<<<138, 128, 0, stream>>>(W3, W4, W34, 138, 128);   // W34 = W3*W4
    genmm<<<138, 128, 0, stream>>>(W2, W34, U2, 138, 128);   // U2  = W2*W34
    genmm<<<79, 128, 0, stream>>>(W1, U2, Wc, 138, 128);     // Wc  = W1*U2
    genmm<<<1, 138, 0, stream>>>(b1, W2, t1, 138, 138);      // t1  = b1*W2
    genmm<<<1, 128, 0, stream>>>(t1, W34, r1, 138, 128);     // r1  = b1*W2*W3*W4
    genmm<<<1, 128, 0, stream>>>(b2, W34, r2, 138, 128);     // r2  = b2*W3*W4
    genmm<<<1, 128, 0, stream>>>(b3, W4, r3, 138, 128);      // r3  = b3*W4
    k_wx<<<128, 96, 0, stream>>>(Wc, r1, r2, r3, b4, WxT);

    // ---- input table T0 (prescaled, col79 = dinv) ----
    {
        dim3 b(SIN, 4);
        k_xconv<<<NN / 4, b, 0, stream>>>(x, ip, dinvp, Xt);
    }

    const int blocks = NN / 128;   // 4096

    // ---- 4 pure aggregations: T0->T1->T2->T3->T4 (snapshots u1,u2,u3) ----
    k_agg_s<1><<<blocks, 512, 0, stream>>>(Xt, HA, u1, rp, colix, dinvp);
    k_agg_s<1><<<blocks, 512, 0, stream>>>(HA, HB, u2, rp, colix, dinvp);
    k_agg_s<1><<<blocks, 512, 0, stream>>>(HB, HA, u3, rp, colix, dinvp);
    k_agg_s<0><<<blocks, 512, 0, stream>>>(HA, HB, nullptr, rp, colix, dinvp);  // T4 unprescaled

    // ---- final GEMM + pad ----
    k_out<<<blocks, 512, 0, stream>>>(HB, WxT, u1, u2, u3, (float*)d_out, perm);
    {
        size_t total = (size_t)NGRAPH * (PADR - GSZ) * F_OUT;
        k_padzero<<<(unsigned)((total + 255) / 256), 256, 0, stream>>>((float*)d_out);
    }
}

// Round 10
// 972.476 us; speedup vs baseline: 1.2961x; 1.1225x over previous
//
#include <hip/hip_runtime.h>

#define NN      524288      // nodes
#define NE      2097152     // edges
#define NGRAPH  16384
#define GSZ     32
#define PADR    45
#define F_IN    79
#define F_MID   138
#define F_OUT   128

#define NSTR    256         // cursor stripes for counting sort
#define SIN     80          // table stride (79 X cols + 1 "ones" col)

typedef __attribute__((ext_vector_type(8))) short short8;
typedef __attribute__((ext_vector_type(4))) float f32x4;

__device__ __forceinline__ unsigned short f2b(float f) {
    union { float f; unsigned u; } v; v.f = f;
    unsigned r = v.u + 0x7FFF + ((v.u >> 16) & 1);   // RNE
    return (unsigned short)(r >> 16);
}
__device__ __forceinline__ float b2f(unsigned short u) {
    union { unsigned u; float f; } v; v.u = ((unsigned)u) << 16;
    return v.f;
}

// ---------------- init: cnt=1 (self loop) + zero hist ----------------

__global__ void k_init(int* __restrict__ cnt, int* __restrict__ hist2) {
    int i = blockIdx.x * 256 + threadIdx.x;
    if (i < NN) cnt[i] = 1;
    if (i < NSTR * 64) hist2[i] = 0;
}

__global__ void k_count(const int* __restrict__ dst, int* __restrict__ cnt) {
    int e = blockIdx.x * 256 + threadIdx.x;
    if (e < NE) atomicAdd(&cnt[dst[e]], 1);
}

// ---------------- degree-balanced permutation (striped counting sort, DESCENDING = LPT) ----------------

__global__ void k_hist2(const int* __restrict__ cnt, int* __restrict__ hist2) {
    int i = blockIdx.x * 256 + threadIdx.x;
    if (i < NN) {
        int d = min(cnt[i], 63);
        atomicAdd(&hist2[(blockIdx.x & (NSTR - 1)) * 64 + d], 1);
    }
}

// exclusive scan in rank order; rank = DESCENDING degree major, stripe minor (LPT)
__global__ void k_sscan(const int* __restrict__ hist2, int* __restrict__ cur) {
    __shared__ int sh[NSTR * 64];
    __shared__ int s[256];
    int t = threadIdx.x;
    for (int i = t; i < NSTR * 64; i += 256) sh[i] = hist2[i];
    __syncthreads();
    int sum = 0;
    for (int k = 0; k < 64; ++k) {
        int r = t * 64 + k;
        int d = 63 - (r >> 8), stripe = r & (NSTR - 1);
        sum += sh[stripe * 64 + d];
    }
    s[t] = sum;
    __syncthreads();
    for (int off = 1; off < 256; off <<= 1) {
        int u = (t >= off) ? s[t - off] : 0;
        __syncthreads();
        s[t] += u;
        __syncthreads();
    }
    int run = s[t] - sum;
    for (int k = 0; k < 64; ++k) {
        int r = t * 64 + k;
        int d = 63 - (r >> 8), stripe = r & (NSTR - 1);
        cur[stripe * 64 + d] = run;
        run += sh[stripe * 64 + d];
    }
}

__global__ void k_scatter2(const int* __restrict__ cnt, int* __restrict__ cur,
                           int* __restrict__ perm, int* __restrict__ ip,
                           float* __restrict__ dinvp) {
    int i = blockIdx.x * 256 + threadIdx.x;
    if (i < NN) {
        int d = min(cnt[i], 63);
        int pos = atomicAdd(&cur[(blockIdx.x & (NSTR - 1)) * 64 + d], 1);
        perm[pos] = i;
        ip[i] = pos;
        dinvp[pos] = rsqrtf((float)cnt[i]);
    }
}

// ---------------- CSR over permuted rows (EDGES ONLY, no self loops) ----------------

__global__ void k_scan1p(const int* __restrict__ cnt, const int* __restrict__ perm,
                         int* __restrict__ rp, int* __restrict__ bsum) {
    __shared__ int s[256];
    int tid = threadIdx.x;
    size_t base = (size_t)blockIdx.x * 1024 + (size_t)tid * 4;
    int c0 = cnt[perm[base + 0]] - 1, c1 = cnt[perm[base + 1]] - 1;
    int c2 = cnt[perm[base + 2]] - 1, c3 = cnt[perm[base + 3]] - 1;
    int tsum = c0 + c1 + c2 + c3;
    s[tid] = tsum;
    __syncthreads();
    for (int off = 1; off < 256; off <<= 1) {
        int t = (tid >= off) ? s[tid - off] : 0;
        __syncthreads();
        s[tid] += t;
        __syncthreads();
    }
    int incl = s[tid];
    int ex = incl - tsum;
    rp[base + 0] = ex;
    rp[base + 1] = ex + c0;
    rp[base + 2] = ex + c0 + c1;
    rp[base + 3] = ex + c0 + c1 + c2;
    if (tid == 255) bsum[blockIdx.x] = incl;
}

__global__ void k_scan2(int* __restrict__ bsum) {
    __shared__ int s[512];
    int tid = threadIdx.x;
    int v = bsum[tid];
    s[tid] = v;
    __syncthreads();
    for (int off = 1; off < 512; off <<= 1) {
        int t = (tid >= off) ? s[tid - off] : 0;
        __syncthreads();
        s[tid] += t;
        __syncthreads();
    }
    bsum[tid] = s[tid] - v;                      // exclusive
}

__global__ void k_scan3(int* __restrict__ rp, const int* __restrict__ bsum,
                        int* __restrict__ cursor) {
    int i = blockIdx.x * 256 + threadIdx.x;
    if (i < NN) {
        int v = rp[i] + bsum[i >> 10];
        rp[i] = v;
        cursor[i] = v;
        if (i == 0) rp[NN] = NE;
    }
}

__global__ void k_fill_edges(const int* __restrict__ src, const int* __restrict__ dst,
                             const int* __restrict__ ip,
                             int* __restrict__ cursor, int* __restrict__ col) {
    int e = blockIdx.x * 256 + threadIdx.x;
    if (e < NE) {
        int r = ip[dst[e]], c = ip[src[e]];
        int s = atomicAdd(&cursor[r], 1);
        col[s] = c;
    }
}

// ---------------- composite weights: C[M,N]=A*B with extra bias row ----------------
// grid = M+1 blocks; block m<M computes C[m,:] = A[m,:]·B; block M computes cv = av·B.
__global__ void k_mm2(const float* __restrict__ A, const float* __restrict__ av,
                      const float* __restrict__ B, float* __restrict__ C,
                      float* __restrict__ cv, int M, int K, int N) {
    int m = blockIdx.x, n = threadIdx.x;
    const float* ar = (m < M) ? (A + (size_t)m * K) : av;
    float s = 0.f;
    for (int k = 0; k < K; ++k) s += ar[k] * B[(size_t)k * N + n];
    if (m < M) C[(size_t)m * N + n] = s;
    else       cv[n] = s;
}

// ---------------- build Wx^T [128 out][96 k] bf16 ----------------
// k<79: Wc[k][c]; 79:0; 80:r3 (pairs u1); 81:r2 (u2); 82:r1 (u3); 83:b4; >=84:0
__global__ void k_wx(const float* __restrict__ Wc, const float* __restrict__ r1,
                     const float* __restrict__ r2, const float* __restrict__ r3,
                     const float* __restrict__ b4, unsigned short* __restrict__ WxT) {
    int c = blockIdx.x, k = threadIdx.x;
    float v = 0.f;
    if (k < 79)       v = Wc[(size_t)k * 128 + c];
    else if (k == 80) v = r3[c];
    else if (k == 81) v = r2[c];
    else if (k == 82) v = r1[c];
    else if (k == 83) v = b4[c];
    WxT[(size_t)c * 96 + k] = f2b(v);
}

// Xt[ip[n]][c] = bf16(dinv * x[n][c]); col 79 = bf16(dinv * 1)
__global__ void k_xconv(const float* __restrict__ x, const int* __restrict__ ip,
                        const float* __restrict__ dinvp, unsigned short* __restrict__ Xt) {
    int n = blockIdx.x * 4 + threadIdx.y;
    int c = threadIdx.x;            // 0..79
    int t = ip[n];
    float d = dinvp[t];
    float v = (c < F_IN) ? d * x[(size_t)n * F_IN + c] : d;
    Xt[(size_t)t * SIN + c] = f2b(v);
}

// ---------------- pure aggregation: T_{k+1} = A T_k on 80-col bf16 table ----------------
// Hin rows prescaled by dinv; output re-prescaled. usnap captures col-79 value (= A^k 1).
__global__ __launch_bounds__(512) void
k_agg_s(const unsigned short* __restrict__ Hin, unsigned short* __restrict__ Hout,
        float* __restrict__ usnap,
        const int* __restrict__ rp, const int* __restrict__ col,
        const float* __restrict__ dinvp) {
    const int tid = threadIdx.x;
    const int wv = tid >> 6, lane = tid & 63;
    const int lrow = lane & 15, kg = lane >> 4;
    const int row = blockIdx.x * 128 + wv * 16 + lrow;
    const int beg = rp[row], end = rp[row + 1];

    float acc[3][8];
#pragma unroll
    for (int ks = 0; ks < 3; ++ks)
#pragma unroll
        for (int e = 0; e < 8; ++e) acc[ks][e] = 0.f;

    // self row (coalesced)
    {
        const unsigned short* hj = Hin + (size_t)row * SIN + kg * 8;
        short8 v0 = *(const short8*)(hj);
        short8 v1 = *(const short8*)(hj + 32);
#pragma unroll
        for (int e = 0; e < 8; ++e) acc[0][e] += b2f((unsigned short)v0[e]);
#pragma unroll
        for (int e = 0; e < 8; ++e) acc[1][e] += b2f((unsigned short)v1[e]);
        if (kg < 2) {
            short8 v2 = *(const short8*)(hj + 64);
#pragma unroll
            for (int e = 0; e < 8; ++e) acc[2][e] += b2f((unsigned short)v2[e]);
        }
    }

    // edge gather, 2-edge staged
    int s = beg;
    for (; s + 1 < end; s += 2) {
        int j0 = col[s], j1 = col[s + 1];
        const unsigned short* h0 = Hin + (size_t)j0 * SIN + kg * 8;
        const unsigned short* h1 = Hin + (size_t)j1 * SIN + kg * 8;
        short8 a0 = *(const short8*)(h0);
        short8 b0 = *(const short8*)(h0 + 32);
        short8 a1 = *(const short8*)(h1);
        short8 b1 = *(const short8*)(h1 + 32);
        if (kg < 2) {
            short8 c0 = *(const short8*)(h0 + 64);
            short8 c1 = *(const short8*)(h1 + 64);
#pragma unroll
            for (int e = 0; e < 8; ++e)
                acc[2][e] += b2f((unsigned short)c0[e]) + b2f((unsigned short)c1[e]);
        }
#pragma unroll
        for (int e = 0; e < 8; ++e)
            acc[0][e] += b2f((unsigned short)a0[e]) + b2f((unsigned short)a1[e]);
#pragma unroll
        for (int e = 0; e < 8; ++e)
            acc[1][e] += b2f((unsigned short)b0[e]) + b2f((unsigned short)b1[e]);
    }
    if (s < end) {
        int j = col[s];
        const unsigned short* hj = Hin + (size_t)j * SIN + kg * 8;
        short8 v0 = *(const short8*)(hj);
        short8 v1 = *(const short8*)(hj + 32);
#pragma unroll
        for (int e = 0; e < 8; ++e) acc[0][e] += b2f((unsigned short)v0[e]);
#pragma unroll
        for (int e = 0; e < 8; ++e) acc[1][e] += b2f((unsigned short)v1[e]);
        if (kg < 2) {
            short8 v2 = *(const short8*)(hj + 64);
#pragma unroll
            for (int e = 0; e < 8; ++e) acc[2][e] += b2f((unsigned short)v2[e]);
        }
    }

    const float di = dinvp[row];
    const float d2 = di * di;
    unsigned short* ho = Hout + (size_t)row * SIN + kg * 8;
#pragma unroll
    for (int ks = 0; ks < 2; ++ks) {
        short8 o;
#pragma unroll
        for (int e = 0; e < 8; ++e) o[e] = (short)f2b(d2 * acc[ks][e]);
        *(short8*)(ho + ks * 32) = o;
    }
    if (kg < 2) {
        short8 o;
#pragma unroll
        for (int e = 0; e < 8; ++e) o[e] = (short)f2b(d2 * acc[2][e]);
        *(short8*)(ho + 64) = o;
        if (kg == 1) usnap[row] = di * acc[2][7];   // col-79 value = A^k 1
    }
}

// ---------------- fused 4th aggregation + final GEMM: Y = [A*T3 | u1 u2 u3 1] @ Wx ----------------
__global__ __launch_bounds__(512) void
k_agg_out(const unsigned short* __restrict__ Hin, const unsigned short* __restrict__ WxT,
          const float* __restrict__ u1, const float* __restrict__ u2,
          const float* __restrict__ u3, float* __restrict__ Yo,
          const int* __restrict__ rp, const int* __restrict__ col,
          const float* __restrict__ dinvp, const int* __restrict__ perm) {
    constexpr int ROWB = 192;                    // 96 cols * 2B
    __shared__ __align__(16) unsigned short Ws[128 * 96];

    const int tid = threadIdx.x;
    for (int i = tid; i < 128 * 96 / 8; i += 512) {
        int r = i / 12, cc = i % 12;
        int bo = cc * 16;
        int so = (bo < 128) ? (bo ^ ((r & 7) << 4)) : bo;
        *(f32x4*)((char*)Ws + (size_t)r * ROWB + so) =
            *(const f32x4*)&WxT[(size_t)r * 96 + cc * 8];
    }

    const int wv = tid >> 6, lane = tid & 63;
    const int lrow = lane & 15, kg = lane >> 4;
    const int row = blockIdx.x * 128 + wv * 16 + lrow;
    const int beg = rp[row], end = rp[row + 1];

    float acc[3][8];
#pragma unroll
    for (int ks = 0; ks < 3; ++ks)
#pragma unroll
        for (int e = 0; e < 8; ++e) acc[ks][e] = 0.f;

    // self row
    {
        const unsigned short* hj = Hin + (size_t)row * SIN + kg * 8;
        short8 v0 = *(const short8*)(hj);
        short8 v1 = *(const short8*)(hj + 32);
#pragma unroll
        for (int e = 0; e < 8; ++e) acc[0][e] += b2f((unsigned short)v0[e]);
#pragma unroll
        for (int e = 0; e < 8; ++e) acc[1][e] += b2f((unsigned short)v1[e]);
        if (kg < 2) {
            short8 v2 = *(const short8*)(hj + 64);
#pragma unroll
            for (int e = 0; e < 8; ++e) acc[2][e] += b2f((unsigned short)v2[e]);
        }
    }
    // edge gather
    int s = beg;
    for (; s + 1 < end; s += 2) {
        int j0 = col[s], j1 = col[s + 1];
        const unsigned short* h0 = Hin + (size_t)j0 * SIN + kg * 8;
        const unsigned short* h1 = Hin + (size_t)j1 * SIN + kg * 8;
        short8 a0 = *(const short8*)(h0);
        short8 b0 = *(const short8*)(h0 + 32);
        short8 a1 = *(const short8*)(h1);
        short8 b1 = *(const short8*)(h1 + 32);
        if (kg < 2) {
            short8 c0 = *(const short8*)(h0 + 64);
            short8 c1 = *(const short8*)(h1 + 64);
#pragma unroll
            for (int e = 0; e < 8; ++e)
                acc[2][e] += b2f((unsigned short)c0[e]) + b2f((unsigned short)c1[e]);
        }
#pragma unroll
        for (int e = 0; e < 8; ++e)
            acc[0][e] += b2f((unsigned short)a0[e]) + b2f((unsigned short)a1[e]);
#pragma unroll
        for (int e = 0; e < 8; ++e)
            acc[1][e] += b2f((unsigned short)b0[e]) + b2f((unsigned short)b1[e]);
    }
    if (s < end) {
        int j = col[s];
        const unsigned short* hj = Hin + (size_t)j * SIN + kg * 8;
        short8 v0 = *(const short8*)(hj);
        short8 v1 = *(const short8*)(hj + 32);
#pragma unroll
        for (int e = 0; e < 8; ++e) acc[0][e] += b2f((unsigned short)v0[e]);
#pragma unroll
        for (int e = 0; e < 8; ++e) acc[1][e] += b2f((unsigned short)v1[e]);
        if (kg < 2) {
            short8 v2 = *(const short8*)(hj + 64);
#pragma unroll
            for (int e = 0; e < 8; ++e) acc[2][e] += b2f((unsigned short)v2[e]);
        }
    }

    // A-fragments: T4 row slice (bf16) + u columns
    const float di = dinvp[row];
    short8 a[3];
#pragma unroll
    for (int ks = 0; ks < 2; ++ks)
#pragma unroll
        for (int e = 0; e < 8; ++e) a[ks][e] = (short)f2b(di * acc[ks][e]);
    if (kg < 2) {
#pragma unroll
        for (int e = 0; e < 8; ++e) a[2][e] = (short)f2b(di * acc[2][e]);
    } else if (kg == 2) {
        a[2][0] = (short)f2b(u1[row]);
        a[2][1] = (short)f2b(u2[row]);
        a[2][2] = (short)f2b(u3[row]);
        a[2][3] = (short)0x3F80;                 // bf16(1.0)
#pragma unroll
        for (int e = 4; e < 8; ++e) a[2][e] = 0;
    } else {
#pragma unroll
        for (int e = 0; e < 8; ++e) a[2][e] = 0;
    }

    __syncthreads();

    f32x4 acc2[8];
#pragma unroll
    for (int n = 0; n < 8; ++n) acc2[n] = (f32x4){0.f, 0.f, 0.f, 0.f};

#pragma unroll
    for (int ks = 0; ks < 3; ++ks) {
        const int bo = ks * 64 + kg * 16;
#pragma unroll
        for (int n = 0; n < 8; ++n) {
            int r = n * 16 + lrow;
            int so = (bo < 128) ? (bo ^ ((r & 7) << 4)) : bo;
            short8 b = *(const short8*)((const char*)Ws + (size_t)r * ROWB + so);
            acc2[n] = __builtin_amdgcn_mfma_f32_16x16x32_bf16(a[ks], b, acc2[n], 0, 0, 0);
        }
    }

    const int t0 = blockIdx.x * 128 + wv * 16 + kg * 4;
    int pr[4];
#pragma unroll
    for (int j = 0; j < 4; ++j) pr[j] = perm[t0 + j];
#pragma unroll
    for (int n = 0; n < 8; ++n) {
        int c = n * 16 + lrow;
#pragma unroll
        for (int j = 0; j < 4; ++j) {
            size_t o = ((size_t)(pr[j] >> 5) * PADR + (pr[j] & 31)) * F_OUT + c;
            __builtin_nontemporal_store(acc2[n][j], &Yo[o]);
        }
    }
}

__global__ void k_padzero(float* __restrict__ out) {
    size_t idx = (size_t)blockIdx.x * 256 + threadIdx.x;
    const size_t total = (size_t)NGRAPH * (PADR - GSZ) * F_OUT;
    if (idx < total) {
        size_t b  = idx / ((PADR - GSZ) * F_OUT);
        int rem   = (int)(idx % ((PADR - GSZ) * F_OUT));
        int r     = GSZ + rem / F_OUT;
        int d     = rem % F_OUT;
        __builtin_nontemporal_store(0.f, &out[((size_t)b * PADR + r) * (size_t)F_OUT + d]);
    }
}

// ---------------- launch ----------------

static inline size_t align256(size_t x) { return (x + 255) & ~(size_t)255; }

extern "C" void kernel_launch(void* const* d_in, const int* in_sizes, int n_in,
                              void* d_out, int out_size, void* d_ws, size_t ws_size,
                              hipStream_t stream) {
    const float* x   = (const float*)d_in[0];
    const int* ei    = (const int*)d_in[1];
    const int* src   = ei;            // edge_index[0]
    const int* dst   = ei + NE;       // edge_index[1]
    const float* W1  = (const float*)d_in[2];
    const float* b1  = (const float*)d_in[3];
    const float* W2  = (const float*)d_in[4];
    const float* b2  = (const float*)d_in[5];
    const float* W3  = (const float*)d_in[6];
    const float* b3  = (const float*)d_in[7];
    const float* W4  = (const float*)d_in[8];
    const float* b4  = (const float*)d_in[9];

    // workspace layout
    char* p = (char*)d_ws;
    unsigned short* HA = (unsigned short*)p;  p += align256((size_t)NN * SIN * 2);
    unsigned short* HB = (unsigned short*)p;  p += align256((size_t)NN * SIN * 2);
    int* cnt    = (int*)p;              p += align256((size_t)NN * sizeof(int));
    int* rp     = (int*)p;              p += align256(((size_t)NN + 1) * sizeof(int));
    int* cursor = (int*)p;              p += align256((size_t)NN * sizeof(int));
    int* colix  = (int*)p;              p += align256((size_t)NE * sizeof(int));
    float* dinvp= (float*)p;            p += align256((size_t)NN * sizeof(float));
    int* perm   = (int*)p;              p += align256((size_t)NN * sizeof(int));
    int* ip     = (int*)p;              p += align256((size_t)NN * sizeof(int));
    int* hist2  = (int*)p;              p += align256((size_t)NSTR * 64 * sizeof(int));
    int* cur    = (int*)p;              p += align256((size_t)NSTR * 64 * sizeof(int));
    int* bsum   = (int*)p;              p += align256(512 * sizeof(int));
    float* u1   = (float*)p;            p += align256((size_t)NN * sizeof(float));
    float* u2   = (float*)p;            p += align256((size_t)NN * sizeof(float));
    float* u3   = (float*)p;            p += align256((size_t)NN * sizeof(float));
    float* P34  = (float*)p;            p += align256(138 * 128 * sizeof(float));
    float* Q2   = (float*)p;            p += align256(138 * 128 * sizeof(float));
    float* Wc   = (float*)p;            p += align256(79 * 128 * sizeof(float));
    float* r1   = (float*)p;            p += align256(128 * sizeof(float));
    float* r2   = (float*)p;            p += align256(128 * sizeof(float));
    float* r3   = (float*)p;            p += align256(128 * sizeof(float));
    unsigned short* WxT = (unsigned short*)p; p += align256(128 * 96 * 2);
    (void)ws_size; (void)n_in; (void)in_sizes; (void)out_size;

    unsigned short* Xt = (unsigned short*)d_out;   // T0 table in d_out scratch

    // ---- degree count + striped counting sort (descending = LPT) ----
    k_init<<<NN / 256, 256, 0, stream>>>(cnt, hist2);
    k_count<<<NE / 256, 256, 0, stream>>>(dst, cnt);
    k_hist2<<<NN / 256, 256, 0, stream>>>(cnt, hist2);
    k_sscan<<<1, 256, 0, stream>>>(hist2, cur);
    k_scatter2<<<NN / 256, 256, 0, stream>>>(cnt, cur, perm, ip, dinvp);

    // ---- CSR in permuted space (edges only) ----
    k_scan1p<<<NN / 1024, 256, 0, stream>>>(cnt, perm, rp, bsum);
    k_scan2<<<1, 512, 0, stream>>>(bsum);
    k_scan3<<<NN / 256, 256, 0, stream>>>(rp, bsum, cursor);
    k_fill_edges<<<NE / 256, 256, 0, stream>>>(src, dst, ip, cursor, colix);

    // ---- composite weights: P=W3W4,r3=b3W4 ; Q=W2P,r2=b2P ; Wc=W1Q,r1=b1Q ----
    k_mm2<<<139, 128, 0, stream>>>(W3, b3, W4, P34, r3, 138, 138, 128);
    k_mm2<<<139, 128, 0, stream>>>(W2, b2, P34, Q2, r2, 138, 138, 128);
    k_mm2<<<80, 128, 0, stream>>>(W1, b1, Q2, Wc, r1, 79, 138, 128);
    k_wx<<<128, 96, 0, stream>>>(Wc, r1, r2, r3, b4, WxT);

    // ---- input table T0 (prescaled, col79 = dinv) ----
    {
        dim3 b(SIN, 4);
        k_xconv<<<NN / 4, b, 0, stream>>>(x, ip, dinvp, Xt);
    }

    const int blocks = NN / 128;   // 4096

    // ---- 3 pure aggregations + fused 4th+GEMM ----
    k_agg_s<<<blocks, 512, 0, stream>>>(Xt, HA, u1, rp, colix, dinvp);
    k_agg_s<<<blocks, 512, 0, stream>>>(HA, HB, u2, rp, colix, dinvp);
    k_agg_s<<<blocks, 512, 0, stream>>>(HB, HA, u3, rp, colix, dinvp);
    k_agg_out<<<blocks, 512, 0, stream>>>(HA, WxT, u1, u2, u3, (float*)d_out,
                                          rp, colix, dinvp, perm);
    {
        size_t total = (size_t)NGRAPH * (PADR - GSZ) * F_OUT;
        k_padzero<<<(unsigned)((total + 255) / 256), 256, 0, stream>>>((float*)d_out);
    }
}

// Round 11
// 941.440 us; speedup vs baseline: 1.3389x; 1.0330x over previous
//
#include <hip/hip_runtime.h>

#define NN      524288      // nodes
#define NE      2097152     // edges
#define NGRAPH  16384
#define GSZ     32
#define PADR    45
#define F_IN    79
#define F_MID   138
#define F_OUT   128

#define NSTR    256         // cursor stripes for counting sort
#define SIN     80          // table stride (79 X cols + 1 "ones" col)

typedef __attribute__((ext_vector_type(8))) short short8;
typedef __attribute__((ext_vector_type(4))) float f32x4;

__device__ __forceinline__ unsigned short f2b(float f) {
    union { float f; unsigned u; } v; v.f = f;
    unsigned r = v.u + 0x7FFF + ((v.u >> 16) & 1);   // RNE
    return (unsigned short)(r >> 16);
}
__device__ __forceinline__ float b2f(unsigned short u) {
    union { unsigned u; float f; } v; v.u = ((unsigned)u) << 16;
    return v.f;
}

// ---------------- init: cnt=1 (self loop) + zero hist ----------------

__global__ void k_init(int* __restrict__ cnt, int* __restrict__ hist2) {
    int i = blockIdx.x * 256 + threadIdx.x;
    if (i < NN) cnt[i] = 1;
    if (i < NSTR * 64) hist2[i] = 0;
}

__global__ void k_count(const int* __restrict__ dst, int* __restrict__ cnt) {
    int e = blockIdx.x * 256 + threadIdx.x;
    if (e < NE) atomicAdd(&cnt[dst[e]], 1);
}

// ---------------- degree-balanced permutation (striped counting sort, DESCENDING = LPT) ----------------

__global__ void k_hist2(const int* __restrict__ cnt, int* __restrict__ hist2) {
    int i = blockIdx.x * 256 + threadIdx.x;
    if (i < NN) {
        int d = min(cnt[i], 63);
        atomicAdd(&hist2[(blockIdx.x & (NSTR - 1)) * 64 + d], 1);
    }
}

// exclusive scan in rank order; rank = DESCENDING degree major, stripe minor (LPT)
__global__ void k_sscan(const int* __restrict__ hist2, int* __restrict__ cur) {
    __shared__ int sh[NSTR * 64];
    __shared__ int s[256];
    int t = threadIdx.x;
    for (int i = t; i < NSTR * 64; i += 256) sh[i] = hist2[i];
    __syncthreads();
    int sum = 0;
    for (int k = 0; k < 64; ++k) {
        int r = t * 64 + k;
        int d = 63 - (r >> 8), stripe = r & (NSTR - 1);
        sum += sh[stripe * 64 + d];
    }
    s[t] = sum;
    __syncthreads();
    for (int off = 1; off < 256; off <<= 1) {
        int u = (t >= off) ? s[t - off] : 0;
        __syncthreads();
        s[t] += u;
        __syncthreads();
    }
    int run = s[t] - sum;
    for (int k = 0; k < 64; ++k) {
        int r = t * 64 + k;
        int d = 63 - (r >> 8), stripe = r & (NSTR - 1);
        cur[stripe * 64 + d] = run;
        run += sh[stripe * 64 + d];
    }
}

__global__ void k_scatter2(const int* __restrict__ cnt, int* __restrict__ cur,
                           int* __restrict__ perm, int* __restrict__ ip,
                           float* __restrict__ dinvp, int* __restrict__ degp) {
    int i = blockIdx.x * 256 + threadIdx.x;
    if (i < NN) {
        int c = cnt[i];
        int d = min(c, 63);
        int pos = atomicAdd(&cur[(blockIdx.x & (NSTR - 1)) * 64 + d], 1);
        perm[pos] = i;
        ip[i] = pos;
        dinvp[pos] = rsqrtf((float)c);
        degp[pos] = c - 1;                       // edge count (no self loop)
    }
}

// ---------------- CSR over permuted rows (EDGES ONLY) ----------------

__global__ void k_scan1p(const int* __restrict__ degp, int* __restrict__ rp,
                         int* __restrict__ bsum) {
    __shared__ int s[256];
    int tid = threadIdx.x;
    size_t base = (size_t)blockIdx.x * 1024 + (size_t)tid * 4;
    int c0 = degp[base + 0], c1 = degp[base + 1];
    int c2 = degp[base + 2], c3 = degp[base + 3];
    int tsum = c0 + c1 + c2 + c3;
    s[tid] = tsum;
    __syncthreads();
    for (int off = 1; off < 256; off <<= 1) {
        int t = (tid >= off) ? s[tid - off] : 0;
        __syncthreads();
        s[tid] += t;
        __syncthreads();
    }
    int incl = s[tid];
    int ex = incl - tsum;
    rp[base + 0] = ex;
    rp[base + 1] = ex + c0;
    rp[base + 2] = ex + c0 + c1;
    rp[base + 3] = ex + c0 + c1 + c2;
    if (tid == 255) bsum[blockIdx.x] = incl;
}

__global__ void k_scan2(int* __restrict__ bsum) {
    __shared__ int s[512];
    int tid = threadIdx.x;
    int v = bsum[tid];
    s[tid] = v;
    __syncthreads();
    for (int off = 1; off < 512; off <<= 1) {
        int t = (tid >= off) ? s[tid - off] : 0;
        __syncthreads();
        s[tid] += t;
        __syncthreads();
    }
    bsum[tid] = s[tid] - v;                      // exclusive
}

__global__ void k_scan3(int* __restrict__ rp, const int* __restrict__ bsum,
                        int* __restrict__ cursor) {
    int i = blockIdx.x * 256 + threadIdx.x;
    if (i < NN) {
        int v = rp[i] + bsum[i >> 10];
        rp[i] = v;
        cursor[i] = v;
        if (i == 0) rp[NN] = NE;
    }
}

__global__ void k_fill_edges(const int* __restrict__ src, const int* __restrict__ dst,
                             const int* __restrict__ ip,
                             int* __restrict__ cursor, int* __restrict__ col) {
    int e = blockIdx.x * 256 + threadIdx.x;
    if (e < NE) {
        int r = ip[dst[e]], c = ip[src[e]];
        int s = atomicAdd(&cursor[r], 1);
        col[s] = c;
    }
}

// ---------------- composite weights ----------------
// C[M,N]=A*B + bias row: block m<M -> C[m,:]; block M -> cv = av·B
__global__ void k_mm2(const float* __restrict__ A, const float* __restrict__ av,
                      const float* __restrict__ B, float* __restrict__ C,
                      float* __restrict__ cv, int M, int K, int N) {
    int m = blockIdx.x, n = threadIdx.x;
    const float* ar = (m < M) ? (A + (size_t)m * K) : av;
    float s = 0.f;
    for (int k = 0; k < K; ++k) s += ar[k] * B[(size_t)k * N + n];
    if (m < M) C[(size_t)m * N + n] = s;
    else       cv[n] = s;
}

// stage 3: Wc = W1·Q2 (written transposed into WxT), bias row r1 = b1·Q2,
// plus fill WxT cols 79..95: [0, r3, r2, r1, b4, 0...]
__global__ void k_mm3(const float* __restrict__ W1, const float* __restrict__ b1,
                      const float* __restrict__ Q2, const float* __restrict__ r2,
                      const float* __restrict__ r3, const float* __restrict__ b4,
                      unsigned short* __restrict__ WxT) {
    int m = blockIdx.x, n = threadIdx.x;     // m: 0..79 (79 = bias row), n: 0..127
    const float* ar = (m < 79) ? (W1 + (size_t)m * 138) : b1;
    float s = 0.f;
    for (int k = 0; k < 138; ++k) s += ar[k] * Q2[(size_t)k * 128 + n];
    if (m < 79) {
        WxT[(size_t)n * 96 + m] = f2b(s);
    } else {
        unsigned short* w = WxT + (size_t)n * 96;
        w[79] = 0;
        w[80] = f2b(r3[n]);
        w[81] = f2b(r2[n]);
        w[82] = f2b(s);                      // r1
        w[83] = f2b(b4[n]);
        for (int k = 84; k < 96; ++k) w[k] = 0;
    }
}

// Xt[ip[n]][c] = bf16(dinv * x[n][c]); col 79 = bf16(dinv)
__global__ void k_xconv(const float* __restrict__ x, const int* __restrict__ ip,
                        const float* __restrict__ dinvp, unsigned short* __restrict__ Xt) {
    int n = blockIdx.x * 4 + threadIdx.y;
    int c = threadIdx.x;            // 0..79
    int t = ip[n];
    float d = dinvp[t];
    float v = (c < F_IN) ? d * x[(size_t)n * F_IN + c] : d;
    Xt[(size_t)t * SIN + c] = f2b(v);
}

// ---------------- gather helpers ----------------

__device__ __forceinline__ void g_load(const unsigned short* __restrict__ Hin,
                                       int j, int kg, short8 v[3]) {
    const unsigned short* h = Hin + (size_t)j * SIN + kg * 8;
    v[0] = *(const short8*)(h);
    v[1] = *(const short8*)(h + 32);
    if (kg < 2) v[2] = *(const short8*)(h + 64);
}

__device__ __forceinline__ void g_acc(float acc[3][8], const short8 v[3], int kg) {
#pragma unroll
    for (int e = 0; e < 8; ++e) acc[0][e] += b2f((unsigned short)v[0][e]);
#pragma unroll
    for (int e = 0; e < 8; ++e) acc[1][e] += b2f((unsigned short)v[1][e]);
    if (kg < 2) {
#pragma unroll
        for (int e = 0; e < 8; ++e) acc[2][e] += b2f((unsigned short)v[2][e]);
    }
}

// software-pipelined edge gather: issue next pair's loads before consuming current
__device__ __forceinline__ void g_edges(const unsigned short* __restrict__ Hin,
                                        const int* __restrict__ col,
                                        int beg, int end, int kg, float acc[3][8]) {
    int s = beg;
    if ((end - beg) & 1) {                       // odd tail first (wave-uniform via LPT)
        short8 v[3];
        g_load(Hin, col[s], kg, v);
        g_acc(acc, v, kg);
        ++s;
    }
    if (s < end) {
        short8 v0[3], v1[3];
        g_load(Hin, col[s], kg, v0);
        g_load(Hin, col[s + 1], kg, v1);
        s += 2;
        for (; s < end; s += 2) {
            int n0 = col[s], n1 = col[s + 1];
            short8 w0[3], w1[3];
            g_load(Hin, n0, kg, w0);             // issue next loads
            g_load(Hin, n1, kg, w1);
            g_acc(acc, v0, kg);                  // consume current
            g_acc(acc, v1, kg);
#pragma unroll
            for (int q = 0; q < 3; ++q) { v0[q] = w0[q]; v1[q] = w1[q]; }
        }
        g_acc(acc, v0, kg);
        g_acc(acc, v1, kg);
    }
}

// ---------------- pure aggregation: T_{k+1} = A T_k ----------------
__global__ __launch_bounds__(256) void
k_agg_s(const unsigned short* __restrict__ Hin, unsigned short* __restrict__ Hout,
        float* __restrict__ usnap,
        const int* __restrict__ rp, const int* __restrict__ col,
        const float* __restrict__ dinvp) {
    const int tid = threadIdx.x;
    const int wv = tid >> 6, lane = tid & 63;
    const int lrow = lane & 15, kg = lane >> 4;
    const int row = blockIdx.x * 64 + wv * 16 + lrow;
    const int beg = rp[row], end = rp[row + 1];

    short8 sv[3];
    g_load(Hin, row, kg, sv);                    // self row: issue first ...

    float acc[3][8];
#pragma unroll
    for (int ks = 0; ks < 3; ++ks)
#pragma unroll
        for (int e = 0; e < 8; ++e) acc[ks][e] = 0.f;

    g_edges(Hin, col, beg, end, kg, acc);
    g_acc(acc, sv, kg);                          // ... consume last

    const float di = dinvp[row];
    const float d2 = di * di;
    unsigned short* ho = Hout + (size_t)row * SIN + kg * 8;
#pragma unroll
    for (int ks = 0; ks < 2; ++ks) {
        short8 o;
#pragma unroll
        for (int e = 0; e < 8; ++e) o[e] = (short)f2b(d2 * acc[ks][e]);
        *(short8*)(ho + ks * 32) = o;
    }
    if (kg < 2) {
        short8 o;
#pragma unroll
        for (int e = 0; e < 8; ++e) o[e] = (short)f2b(d2 * acc[2][e]);
        *(short8*)(ho + 64) = o;
        if (kg == 1) usnap[row] = di * acc[2][7];   // col-79 value = A^k 1
    }
}

// ---------------- fused 4th aggregation + final GEMM ----------------
__global__ __launch_bounds__(256) void
k_agg_out(const unsigned short* __restrict__ Hin, const unsigned short* __restrict__ WxT,
          const float* __restrict__ u1, const float* __restrict__ u2,
          const float* __restrict__ u3, float* __restrict__ Yo,
          const int* __restrict__ rp, const int* __restrict__ col,
          const float* __restrict__ dinvp, const int* __restrict__ perm) {
    constexpr int ROWB = 192;                    // 96 cols * 2B
    __shared__ __align__(16) unsigned short Ws[128 * 96];

    const int tid = threadIdx.x;
    for (int i = tid; i < 128 * 96 / 8; i += 256) {
        int r = i / 12, cc = i % 12;
        int bo = cc * 16;
        int so = (bo < 128) ? (bo ^ ((r & 7) << 4)) : bo;
        *(f32x4*)((char*)Ws + (size_t)r * ROWB + so) =
            *(const f32x4*)&WxT[(size_t)r * 96 + cc * 8];
    }

    const int wv = tid >> 6, lane = tid & 63;
    const int lrow = lane & 15, kg = lane >> 4;
    const int row = blockIdx.x * 64 + wv * 16 + lrow;
    const int beg = rp[row], end = rp[row + 1];

    float acc[3][8];
#pragma unroll
    for (int ks = 0; ks < 3; ++ks)
#pragma unroll
        for (int e = 0; e < 8; ++e) acc[ks][e] = 0.f;

    {   // self row first (consumed immediately to conserve VGPRs for MFMA phase)
        short8 sv[3];
        g_load(Hin, row, kg, sv);
        g_acc(acc, sv, kg);
    }
    g_edges(Hin, col, beg, end, kg, acc);

    // A-fragments: T4 row slice (bf16) + u columns
    const float di = dinvp[row];
    short8 a[3];
#pragma unroll
    for (int ks = 0; ks < 2; ++ks)
#pragma unroll
        for (int e = 0; e < 8; ++e) a[ks][e] = (short)f2b(di * acc[ks][e]);
    if (kg < 2) {
#pragma unroll
        for (int e = 0; e < 8; ++e) a[2][e] = (short)f2b(di * acc[2][e]);
    } else if (kg == 2) {
        a[2][0] = (short)f2b(u1[row]);
        a[2][1] = (short)f2b(u2[row]);
        a[2][2] = (short)f2b(u3[row]);
        a[2][3] = (short)0x3F80;                 // bf16(1.0)
#pragma unroll
        for (int e = 4; e < 8; ++e) a[2][e] = 0;
    } else {
#pragma unroll
        for (int e = 0; e < 8; ++e) a[2][e] = 0;
    }

    __syncthreads();

    f32x4 acc2[8];
#pragma unroll
    for (int n = 0; n < 8; ++n) acc2[n] = (f32x4){0.f, 0.f, 0.f, 0.f};

#pragma unroll
    for (int ks = 0; ks < 3; ++ks) {
        const int bo = ks * 64 + kg * 16;
#pragma unroll
        for (int n = 0; n < 8; ++n) {
            int r = n * 16 + lrow;
            int so = (bo < 128) ? (bo ^ ((r & 7) << 4)) : bo;
            short8 b = *(const short8*)((const char*)Ws + (size_t)r * ROWB + so);
            acc2[n] = __builtin_amdgcn_mfma_f32_16x16x32_bf16(a[ks], b, acc2[n], 0, 0, 0);
        }
    }

    const int t0 = blockIdx.x * 64 + wv * 16 + kg * 4;
    int pr[4];
#pragma unroll
    for (int j = 0; j < 4; ++j) pr[j] = perm[t0 + j];
#pragma unroll
    for (int n = 0; n < 8; ++n) {
        int c = n * 16 + lrow;
#pragma unroll
        for (int j = 0; j < 4; ++j) {
            size_t o = ((size_t)(pr[j] >> 5) * PADR + (pr[j] & 31)) * F_OUT + c;
            __builtin_nontemporal_store(acc2[n][j], &Yo[o]);
        }
    }
}

__global__ void k_padzero(float* __restrict__ out) {
    size_t idx = (size_t)blockIdx.x * 256 + threadIdx.x;
    const size_t total = (size_t)NGRAPH * (PADR - GSZ) * F_OUT;
    if (idx < total) {
        size_t b  = idx / ((PADR - GSZ) * F_OUT);
        int rem   = (int)(idx % ((PADR - GSZ) * F_OUT));
        int r     = GSZ + rem / F_OUT;
        int d     = rem % F_OUT;
        __builtin_nontemporal_store(0.f, &out[((size_t)b * PADR + r) * (size_t)F_OUT + d]);
    }
}

// ---------------- launch ----------------

static inline size_t align256(size_t x) { return (x + 255) & ~(size_t)255; }

extern "C" void kernel_launch(void* const* d_in, const int* in_sizes, int n_in,
                              void* d_out, int out_size, void* d_ws, size_t ws_size,
                              hipStream_t stream) {
    const float* x   = (const float*)d_in[0];
    const int* ei    = (const int*)d_in[1];
    const int* src   = ei;            // edge_index[0]
    const int* dst   = ei + NE;       // edge_index[1]
    const float* W1  = (const float*)d_in[2];
    const float* b1  = (const float*)d_in[3];
    const float* W2  = (const float*)d_in[4];
    const float* b2  = (const float*)d_in[5];
    const float* W3  = (const float*)d_in[6];
    const float* b3  = (const float*)d_in[7];
    const float* W4  = (const float*)d_in[8];
    const float* b4  = (const float*)d_in[9];

    // workspace layout
    char* p = (char*)d_ws;
    unsigned short* HA = (unsigned short*)p;  p += align256((size_t)NN * SIN * 2);
    unsigned short* HB = (unsigned short*)p;  p += align256((size_t)NN * SIN * 2);
    int* cnt    = (int*)p;              p += align256((size_t)NN * sizeof(int));
    int* rp     = (int*)p;              p += align256(((size_t)NN + 1) * sizeof(int));
    int* cursor = (int*)p;              p += align256((size_t)NN * sizeof(int));
    int* colix  = (int*)p;              p += align256((size_t)NE * sizeof(int));
    float* dinvp= (float*)p;            p += align256((size_t)NN * sizeof(float));
    int* perm   = (int*)p;              p += align256((size_t)NN * sizeof(int));
    int* ip     = (int*)p;              p += align256((size_t)NN * sizeof(int));
    int* degp   = (int*)p;              p += align256((size_t)NN * sizeof(int));
    int* hist2  = (int*)p;              p += align256((size_t)NSTR * 64 * sizeof(int));
    int* cur    = (int*)p;              p += align256((size_t)NSTR * 64 * sizeof(int));
    int* bsum   = (int*)p;              p += align256(512 * sizeof(int));
    float* u1   = (float*)p;            p += align256((size_t)NN * sizeof(float));
    float* u2   = (float*)p;            p += align256((size_t)NN * sizeof(float));
    float* u3   = (float*)p;            p += align256((size_t)NN * sizeof(float));
    float* P34  = (float*)p;            p += align256(138 * 128 * sizeof(float));
    float* Q2   = (float*)p;            p += align256(138 * 128 * sizeof(float));
    float* r2   = (float*)p;            p += align256(128 * sizeof(float));
    float* r3   = (float*)p;            p += align256(128 * sizeof(float));
    unsigned short* WxT = (unsigned short*)p; p += align256(128 * 96 * 2);
    (void)ws_size; (void)n_in; (void)in_sizes; (void)out_size;

    unsigned short* Xt = (unsigned short*)d_out;   // T0 table in d_out scratch

    // ---- degree count + striped counting sort (descending = LPT) ----
    k_init<<<NN / 256, 256, 0, stream>>>(cnt, hist2);
    k_count<<<NE / 256, 256, 0, stream>>>(dst, cnt);
    k_hist2<<<NN / 256, 256, 0, stream>>>(cnt, hist2);
    k_sscan<<<1, 256, 0, stream>>>(hist2, cur);
    k_scatter2<<<NN / 256, 256, 0, stream>>>(cnt, cur, perm, ip, dinvp, degp);

    // ---- CSR in permuted space (edges only) ----
    k_scan1p<<<NN / 1024, 256, 0, stream>>>(degp, rp, bsum);
    k_scan2<<<1, 512, 0, stream>>>(bsum);
    k_scan3<<<NN / 256, 256, 0, stream>>>(rp, bsum, cursor);
    k_fill_edges<<<NE / 256, 256, 0, stream>>>(src, dst, ip, cursor, colix);

    // ---- composite weights: P=W3W4,r3=b3W4 ; Q=W2P,r2=b2P ; WxT = [W1Q | aux] ----
    k_mm2<<<139, 128, 0, stream>>>(W3, b3, W4, P34, r3, 138, 138, 128);
    k_mm2<<<139, 128, 0, stream>>>(W2, b2, P34, Q2, r2, 138, 138, 128);
    k_mm3<<<80, 128, 0, stream>>>(W1, b1, Q2, r2, r3, b4, WxT);

    // ---- input table T0 (prescaled, col79 = dinv) ----
    {
        dim3 b(SIN, 4);
        k_xconv<<<NN / 4, b, 0, stream>>>(x, ip, dinvp, Xt);
    }

    const int blocks = NN / 64;   // 8192 (64 rows per 256-thread block)

    // ---- 3 pure aggregations + fused 4th+GEMM ----
    k_agg_s<<<blocks, 256, 0, stream>>>(Xt, HA, u1, rp, colix, dinvp);
    k_agg_s<<<blocks, 256, 0, stream>>>(HA, HB, u2, rp, colix, dinvp);
    k_agg_s<<<blocks, 256, 0, stream>>>(HB, HA, u3, rp, colix, dinvp);
    k_agg_out<<<blocks, 256, 0, stream>>>(HA, WxT, u1, u2, u3, (float*)d_out,
                                          rp, colix, dinvp, perm);
    {
        size_t total = (size_t)NGRAPH * (PADR - GSZ) * F_OUT;
        k_padzero<<<(unsigned)((total + 255) / 256), 256, 0, stream>>>((float*)d_out);
    }
}

// Round 12
// 940.946 us; speedup vs baseline: 1.3396x; 1.0005x over previous
//
#include <hip/hip_runtime.h>

#define NN      524288      // nodes
#define NE      2097152     // edges
#define NGRAPH  16384
#define GSZ     32
#define PADR    45
#define F_IN    79
#define F_MID   138
#define F_OUT   128

#define NSTR    256         // cursor stripes for counting sort
#define SIN     80          // table stride (79 X cols + 1 "ones" col)

typedef __attribute__((ext_vector_type(8))) short short8;
typedef __attribute__((ext_vector_type(4))) float f32x4;

__device__ __forceinline__ unsigned short f2b(float f) {
    union { float f; unsigned u; } v; v.f = f;
    unsigned r = v.u + 0x7FFF + ((v.u >> 16) & 1);   // RNE
    return (unsigned short)(r >> 16);
}
__device__ __forceinline__ float b2f(unsigned short u) {
    union { unsigned u; float f; } v; v.u = ((unsigned)u) << 16;
    return v.f;
}

// ---------------- init: cnt=1 (self loop) + zero hist ----------------

__global__ void k_init(int* __restrict__ cnt, int* __restrict__ hist2) {
    int i = blockIdx.x * 256 + threadIdx.x;
    if (i < NN) cnt[i] = 1;
    if (i < NSTR * 64) hist2[i] = 0;
}

__global__ void k_count(const int* __restrict__ dst, int* __restrict__ cnt) {
    int e = blockIdx.x * 256 + threadIdx.x;
    if (e < NE) atomicAdd(&cnt[dst[e]], 1);
}

// ---------------- degree-balanced permutation (striped counting sort, DESCENDING = LPT) ----------------

__global__ void k_hist2(const int* __restrict__ cnt, int* __restrict__ hist2) {
    int i = blockIdx.x * 256 + threadIdx.x;
    if (i < NN) {
        int d = min(cnt[i], 63);
        atomicAdd(&hist2[(blockIdx.x & (NSTR - 1)) * 64 + d], 1);
    }
}

// exclusive scan in rank order; rank = DESCENDING degree major, stripe minor (LPT)
__global__ void k_sscan(const int* __restrict__ hist2, int* __restrict__ cur) {
    __shared__ int sh[NSTR * 64];
    __shared__ int s[256];
    int t = threadIdx.x;
    for (int i = t; i < NSTR * 64; i += 256) sh[i] = hist2[i];
    __syncthreads();
    int sum = 0;
    for (int k = 0; k < 64; ++k) {
        int r = t * 64 + k;
        int d = 63 - (r >> 8), stripe = r & (NSTR - 1);
        sum += sh[stripe * 64 + d];
    }
    s[t] = sum;
    __syncthreads();
    for (int off = 1; off < 256; off <<= 1) {
        int u = (t >= off) ? s[t - off] : 0;
        __syncthreads();
        s[t] += u;
        __syncthreads();
    }
    int run = s[t] - sum;
    for (int k = 0; k < 64; ++k) {
        int r = t * 64 + k;
        int d = 63 - (r >> 8), stripe = r & (NSTR - 1);
        cur[stripe * 64 + d] = run;
        run += sh[stripe * 64 + d];
    }
}

__global__ void k_scatter2(const int* __restrict__ cnt, int* __restrict__ cur,
                           int* __restrict__ perm, int* __restrict__ ip,
                           float* __restrict__ dinvp, int* __restrict__ degp) {
    int i = blockIdx.x * 256 + threadIdx.x;
    if (i < NN) {
        int c = cnt[i];
        int d = min(c, 63);
        int pos = atomicAdd(&cur[(blockIdx.x & (NSTR - 1)) * 64 + d], 1);
        perm[pos] = i;
        ip[i] = pos;
        dinvp[pos] = rsqrtf((float)c);
        degp[pos] = c - 1;                       // edge count (no self loop)
    }
}

// ---------------- CSR over permuted rows (EDGES ONLY) ----------------

__global__ void k_scan1p(const int* __restrict__ degp, int* __restrict__ rp,
                         int* __restrict__ bsum) {
    __shared__ int s[256];
    int tid = threadIdx.x;
    size_t base = (size_t)blockIdx.x * 1024 + (size_t)tid * 4;
    int c0 = degp[base + 0], c1 = degp[base + 1];
    int c2 = degp[base + 2], c3 = degp[base + 3];
    int tsum = c0 + c1 + c2 + c3;
    s[tid] = tsum;
    __syncthreads();
    for (int off = 1; off < 256; off <<= 1) {
        int t = (tid >= off) ? s[tid - off] : 0;
        __syncthreads();
        s[tid] += t;
        __syncthreads();
    }
    int incl = s[tid];
    int ex = incl - tsum;
    rp[base + 0] = ex;
    rp[base + 1] = ex + c0;
    rp[base + 2] = ex + c0 + c1;
    rp[base + 3] = ex + c0 + c1 + c2;
    if (tid == 255) bsum[blockIdx.x] = incl;
}

__global__ void k_scan2(int* __restrict__ bsum) {
    __shared__ int s[512];
    int tid = threadIdx.x;
    int v = bsum[tid];
    s[tid] = v;
    __syncthreads();
    for (int off = 1; off < 512; off <<= 1) {
        int t = (tid >= off) ? s[tid - off] : 0;
        __syncthreads();
        s[tid] += t;
        __syncthreads();
    }
    bsum[tid] = s[tid] - v;                      // exclusive
}

__global__ void k_scan3(int* __restrict__ rp, const int* __restrict__ bsum,
                        int* __restrict__ cursor) {
    int i = blockIdx.x * 256 + threadIdx.x;
    if (i < NN) {
        int v = rp[i] + bsum[i >> 10];
        rp[i] = v;
        cursor[i] = v;
        if (i == 0) rp[NN] = NE;
    }
}

__global__ void k_fill_edges(const int* __restrict__ src, const int* __restrict__ dst,
                             const int* __restrict__ ip,
                             int* __restrict__ cursor, int* __restrict__ col) {
    int e = blockIdx.x * 256 + threadIdx.x;
    if (e < NE) {
        int r = ip[dst[e]], c = ip[src[e]];
        int s = atomicAdd(&cursor[r], 1);
        col[s] = c;
    }
}

// ---------------- composite weights ----------------
// C[M,N]=A*B + bias row: block m<M -> C[m,:]; block M -> cv = av·B
__global__ void k_mm2(const float* __restrict__ A, const float* __restrict__ av,
                      const float* __restrict__ B, float* __restrict__ C,
                      float* __restrict__ cv, int M, int K, int N) {
    int m = blockIdx.x, n = threadIdx.x;
    const float* ar = (m < M) ? (A + (size_t)m * K) : av;
    float s = 0.f;
    for (int k = 0; k < K; ++k) s += ar[k] * B[(size_t)k * N + n];
    if (m < M) C[(size_t)m * N + n] = s;
    else       cv[n] = s;
}

// stage 3: Wc = W1·Q2 (written transposed into WxT), bias row r1 = b1·Q2,
// plus fill WxT cols 79..95: [0, r3, r2, r1, b4, 0...]
__global__ void k_mm3(const float* __restrict__ W1, const float* __restrict__ b1,
                      const float* __restrict__ Q2, const float* __restrict__ r2,
                      const float* __restrict__ r3, const float* __restrict__ b4,
                      unsigned short* __restrict__ WxT) {
    int m = blockIdx.x, n = threadIdx.x;     // m: 0..79 (79 = bias row), n: 0..127
    const float* ar = (m < 79) ? (W1 + (size_t)m * 138) : b1;
    float s = 0.f;
    for (int k = 0; k < 138; ++k) s += ar[k] * Q2[(size_t)k * 128 + n];
    if (m < 79) {
        WxT[(size_t)n * 96 + m] = f2b(s);
    } else {
        unsigned short* w = WxT + (size_t)n * 96;
        w[79] = 0;
        w[80] = f2b(r3[n]);
        w[81] = f2b(r2[n]);
        w[82] = f2b(s);                      // r1
        w[83] = f2b(b4[n]);
        for (int k = 84; k < 96; ++k) w[k] = 0;
    }
}

// Xt[ip[n]][c] = bf16(dinv * x[n][c]); col 79 = bf16(dinv)
__global__ void k_xconv(const float* __restrict__ x, const int* __restrict__ ip,
                        const float* __restrict__ dinvp, unsigned short* __restrict__ Xt) {
    int n = blockIdx.x * 4 + threadIdx.y;
    int c = threadIdx.x;            // 0..79
    int t = ip[n];
    float d = dinvp[t];
    float v = (c < F_IN) ? d * x[(size_t)n * F_IN + c] : d;
    Xt[(size_t)t * SIN + c] = f2b(v);
}

// ---------------- gather helpers ----------------

__device__ __forceinline__ void g_load(const unsigned short* __restrict__ Hin,
                                       int j, int kg, short8 v[3]) {
    const unsigned short* h = Hin + (size_t)j * SIN + kg * 8;
    v[0] = *(const short8*)(h);
    v[1] = *(const short8*)(h + 32);
    if (kg < 2) v[2] = *(const short8*)(h + 64);
}

__device__ __forceinline__ void g_acc(float acc[3][8], const short8 v[3], int kg) {
#pragma unroll
    for (int e = 0; e < 8; ++e) acc[0][e] += b2f((unsigned short)v[0][e]);
#pragma unroll
    for (int e = 0; e < 8; ++e) acc[1][e] += b2f((unsigned short)v[1][e]);
    if (kg < 2) {
#pragma unroll
        for (int e = 0; e < 8; ++e) acc[2][e] += b2f((unsigned short)v[2][e]);
    }
}

// fully-staged batch of B edges: issue ALL loads, then accumulate (1 latency stall)
template<int B>
__device__ __forceinline__ void g_batch(const unsigned short* __restrict__ Hin,
                                        const int* __restrict__ col, int s, int kg,
                                        float acc[3][8]) {
    int j[B];
#pragma unroll
    for (int q = 0; q < B; ++q) j[q] = col[s + q];
    short8 v[B][3];
#pragma unroll
    for (int q = 0; q < B; ++q) g_load(Hin, j[q], kg, v[q]);
#pragma unroll
    for (int q = 0; q < B; ++q) g_acc(acc, v[q], kg);
}

// batched edge gather; degree is wave-uniform (LPT) -> branches are coherent
__device__ __forceinline__ void g_edges(const unsigned short* __restrict__ Hin,
                                        const int* __restrict__ col,
                                        int beg, int end, int kg, float acc[3][8]) {
    int s = beg;
    for (; s + 4 <= end; s += 4) g_batch<4>(Hin, col, s, kg, acc);
    int rem = end - s;
    if (rem == 3)      g_batch<3>(Hin, col, s, kg, acc);
    else if (rem == 2) g_batch<2>(Hin, col, s, kg, acc);
    else if (rem == 1) g_batch<1>(Hin, col, s, kg, acc);
}

// ---------------- pure aggregation: T_{k+1} = A T_k ----------------
__global__ __launch_bounds__(256) void
k_agg_s(const unsigned short* __restrict__ Hin, unsigned short* __restrict__ Hout,
        float* __restrict__ usnap,
        const int* __restrict__ rp, const int* __restrict__ col,
        const float* __restrict__ dinvp) {
    const int tid = threadIdx.x;
    const int wv = tid >> 6, lane = tid & 63;
    const int lrow = lane & 15, kg = lane >> 4;
    const int row = blockIdx.x * 64 + wv * 16 + lrow;
    const int beg = rp[row], end = rp[row + 1];

    short8 sv[3];
    g_load(Hin, row, kg, sv);                    // self row: issue first ...

    float acc[3][8];
#pragma unroll
    for (int ks = 0; ks < 3; ++ks)
#pragma unroll
        for (int e = 0; e < 8; ++e) acc[ks][e] = 0.f;

    g_edges(Hin, col, beg, end, kg, acc);
    g_acc(acc, sv, kg);                          // ... consume last

    const float di = dinvp[row];
    const float d2 = di * di;
    unsigned short* ho = Hout + (size_t)row * SIN + kg * 8;
#pragma unroll
    for (int ks = 0; ks < 2; ++ks) {
        short8 o;
#pragma unroll
        for (int e = 0; e < 8; ++e) o[e] = (short)f2b(d2 * acc[ks][e]);
        *(short8*)(ho + ks * 32) = o;
    }
    if (kg < 2) {
        short8 o;
#pragma unroll
        for (int e = 0; e < 8; ++e) o[e] = (short)f2b(d2 * acc[2][e]);
        *(short8*)(ho + 64) = o;
        if (kg == 1) usnap[row] = di * acc[2][7];   // col-79 value = A^k 1
    }
}

// ---------------- fused 4th aggregation + final GEMM ----------------
__global__ __launch_bounds__(256) void
k_agg_out(const unsigned short* __restrict__ Hin, const unsigned short* __restrict__ WxT,
          const float* __restrict__ u1, const float* __restrict__ u2,
          const float* __restrict__ u3, float* __restrict__ Yo,
          const int* __restrict__ rp, const int* __restrict__ col,
          const float* __restrict__ dinvp, const int* __restrict__ perm) {
    constexpr int ROWB = 192;                    // 96 cols * 2B
    __shared__ __align__(16) unsigned short Ws[128 * 96];

    const int tid = threadIdx.x;
    for (int i = tid; i < 128 * 96 / 8; i += 256) {
        int r = i / 12, cc = i % 12;
        int bo = cc * 16;
        int so = (bo < 128) ? (bo ^ ((r & 7) << 4)) : bo;
        *(f32x4*)((char*)Ws + (size_t)r * ROWB + so) =
            *(const f32x4*)&WxT[(size_t)r * 96 + cc * 8];
    }

    const int wv = tid >> 6, lane = tid & 63;
    const int lrow = lane & 15, kg = lane >> 4;
    const int row = blockIdx.x * 64 + wv * 16 + lrow;
    const int beg = rp[row], end = rp[row + 1];

    float acc[3][8];
#pragma unroll
    for (int ks = 0; ks < 3; ++ks)
#pragma unroll
        for (int e = 0; e < 8; ++e) acc[ks][e] = 0.f;

    {   // self row first
        short8 sv[3];
        g_load(Hin, row, kg, sv);
        g_acc(acc, sv, kg);
    }
    g_edges(Hin, col, beg, end, kg, acc);

    // A-fragments: T4 row slice (bf16) + u columns
    const float di = dinvp[row];
    short8 a[3];
#pragma unroll
    for (int ks = 0; ks < 2; ++ks)
#pragma unroll
        for (int e = 0; e < 8; ++e) a[ks][e] = (short)f2b(di * acc[ks][e]);
    if (kg < 2) {
#pragma unroll
        for (int e = 0; e < 8; ++e) a[2][e] = (short)f2b(di * acc[2][e]);
    } else if (kg == 2) {
        a[2][0] = (short)f2b(u1[row]);
        a[2][1] = (short)f2b(u2[row]);
        a[2][2] = (short)f2b(u3[row]);
        a[2][3] = (short)0x3F80;                 // bf16(1.0)
#pragma unroll
        for (int e = 4; e < 8; ++e) a[2][e] = 0;
    } else {
#pragma unroll
        for (int e = 0; e < 8; ++e) a[2][e] = 0;
    }

    __syncthreads();

    f32x4 acc2[8];
#pragma unroll
    for (int n = 0; n < 8; ++n) acc2[n] = (f32x4){0.f, 0.f, 0.f, 0.f};

#pragma unroll
    for (int ks = 0; ks < 3; ++ks) {
        const int bo = ks * 64 + kg * 16;
#pragma unroll
        for (int n = 0; n < 8; ++n) {
            int r = n * 16 + lrow;
            int so = (bo < 128) ? (bo ^ ((r & 7) << 4)) : bo;
            short8 b = *(const short8*)((const char*)Ws + (size_t)r * ROWB + so);
            acc2[n] = __builtin_amdgcn_mfma_f32_16x16x32_bf16(a[ks], b, acc2[n], 0, 0, 0);
        }
    }

    const int t0 = blockIdx.x * 64 + wv * 16 + kg * 4;
    int pr[4];
#pragma unroll
    for (int j = 0; j < 4; ++j) pr[j] = perm[t0 + j];
#pragma unroll
    for (int n = 0; n < 8; ++n) {
        int c = n * 16 + lrow;
#pragma unroll
        for (int j = 0; j < 4; ++j) {
            size_t o = ((size_t)(pr[j] >> 5) * PADR + (pr[j] & 31)) * F_OUT + c;
            __builtin_nontemporal_store(acc2[n][j], &Yo[o]);
        }
    }
}

__global__ void k_padzero(float* __restrict__ out) {
    size_t idx = (size_t)blockIdx.x * 256 + threadIdx.x;
    const size_t total = (size_t)NGRAPH * (PADR - GSZ) * F_OUT;
    if (idx < total) {
        size_t b  = idx / ((PADR - GSZ) * F_OUT);
        int rem   = (int)(idx % ((PADR - GSZ) * F_OUT));
        int r     = GSZ + rem / F_OUT;
        int d     = rem % F_OUT;
        __builtin_nontemporal_store(0.f, &out[((size_t)b * PADR + r) * (size_t)F_OUT + d]);
    }
}

// ---------------- launch ----------------

static inline size_t align256(size_t x) { return (x + 255) & ~(size_t)255; }

extern "C" void kernel_launch(void* const* d_in, const int* in_sizes, int n_in,
                              void* d_out, int out_size, void* d_ws, size_t ws_size,
                              hipStream_t stream) {
    const float* x   = (const float*)d_in[0];
    const int* ei    = (const int*)d_in[1];
    const int* src   = ei;            // edge_index[0]
    const int* dst   = ei + NE;       // edge_index[1]
    const float* W1  = (const float*)d_in[2];
    const float* b1  = (const float*)d_in[3];
    const float* W2  = (const float*)d_in[4];
    const float* b2  = (const float*)d_in[5];
    const float* W3  = (const float*)d_in[6];
    const float* b3  = (const float*)d_in[7];
    const float* W4  = (const float*)d_in[8];
    const float* b4  = (const float*)d_in[9];

    // workspace layout
    char* p = (char*)d_ws;
    unsigned short* HA = (unsigned short*)p;  p += align256((size_t)NN * SIN * 2);
    unsigned short* HB = (unsigned short*)p;  p += align256((size_t)NN * SIN * 2);
    int* cnt    = (int*)p;              p += align256((size_t)NN * sizeof(int));
    int* rp     = (int*)p;              p += align256(((size_t)NN + 1) * sizeof(int));
    int* cursor = (int*)p;              p += align256((size_t)NN * sizeof(int));
    int* colix  = (int*)p;              p += align256((size_t)NE * sizeof(int));
    float* dinvp= (float*)p;            p += align256((size_t)NN * sizeof(float));
    int* perm   = (int*)p;              p += align256((size_t)NN * sizeof(int));
    int* ip     = (int*)p;              p += align256((size_t)NN * sizeof(int));
    int* degp   = (int*)p;              p += align256((size_t)NN * sizeof(int));
    int* hist2  = (int*)p;              p += align256((size_t)NSTR * 64 * sizeof(int));
    int* cur    = (int*)p;              p += align256((size_t)NSTR * 64 * sizeof(int));
    int* bsum   = (int*)p;              p += align256(512 * sizeof(int));
    float* u1   = (float*)p;            p += align256((size_t)NN * sizeof(float));
    float* u2   = (float*)p;            p += align256((size_t)NN * sizeof(float));
    float* u3   = (float*)p;            p += align256((size_t)NN * sizeof(float));
    float* P34  = (float*)p;            p += align256(138 * 128 * sizeof(float));
    float* Q2   = (float*)p;            p += align256(138 * 128 * sizeof(float));
    float* r2   = (float*)p;            p += align256(128 * sizeof(float));
    float* r3   = (float*)p;            p += align256(128 * sizeof(float));
    unsigned short* WxT = (unsigned short*)p; p += align256(128 * 96 * 2);
    (void)ws_size; (void)n_in; (void)in_sizes; (void)out_size;

    unsigned short* Xt = (unsigned short*)d_out;   // T0 table in d_out scratch

    // ---- degree count + striped counting sort (descending = LPT) ----
    k_init<<<NN / 256, 256, 0, stream>>>(cnt, hist2);
    k_count<<<NE / 256, 256, 0, stream>>>(dst, cnt);
    k_hist2<<<NN / 256, 256, 0, stream>>>(cnt, hist2);
    k_sscan<<<1, 256, 0, stream>>>(hist2, cur);
    k_scatter2<<<NN / 256, 256, 0, stream>>>(cnt, cur, perm, ip, dinvp, degp);

    // ---- CSR in permuted space (edges only) ----
    k_scan1p<<<NN / 1024, 256, 0, stream>>>(degp, rp, bsum);
    k_scan2<<<1, 512, 0, stream>>>(bsum);
    k_scan3<<<NN / 256, 256, 0, stream>>>(rp, bsum, cursor);
    k_fill_edges<<<NE / 256, 256, 0, stream>>>(src, dst, ip, cursor, colix);

    // ---- composite weights: P=W3W4,r3=b3W4 ; Q=W2P,r2=b2P ; WxT = [W1Q | aux] ----
    k_mm2<<<139, 128, 0, stream>>>(W3, b3, W4, P34, r3, 138, 138, 128);
    k_mm2<<<139, 128, 0, stream>>>(W2, b2, P34, Q2, r2, 138, 138, 128);
    k_mm3<<<80, 128, 0, stream>>>(W1, b1, Q2, r2, r3, b4, WxT);

    // ---- input table T0 (prescaled, col79 = dinv) ----
    {
        dim3 b(SIN, 4);
        k_xconv<<<NN / 4, b, 0, stream>>>(x, ip, dinvp, Xt);
    }

    const int blocks = NN / 64;   // 8192 (64 rows per 256-thread block)

    // ---- 3 pure aggregations + fused 4th+GEMM ----
    k_agg_s<<<blocks, 256, 0, stream>>>(Xt, HA, u1, rp, colix, dinvp);
    k_agg_s<<<blocks, 256, 0, stream>>>(HA, HB, u2, rp, colix, dinvp);
    k_agg_s<<<blocks, 256, 0, stream>>>(HB, HA, u3, rp, colix, dinvp);
    k_agg_out<<<blocks, 256, 0, stream>>>(HA, WxT, u1, u2, u3, (float*)d_out,
                                          rp, colix, dinvp, perm);
    {
        size_t total = (size_t)NGRAPH * (PADR - GSZ) * F_OUT;
        k_padzero<<<(unsigned)((total + 255) / 256), 256, 0, stream>>>((float*)d_out);
    }
}